// Round 15
// baseline (276.926 us; speedup 1.0000x reference)
//
#include <hip/hip_runtime.h>

typedef __bf16 bf16;
typedef __attribute__((ext_vector_type(8))) __bf16 bf16x8;
typedef __attribute__((ext_vector_type(4))) __bf16 bf16x4;
typedef __attribute__((ext_vector_type(4))) float f32x4;

#define MFMA16(A, B, C) __builtin_amdgcn_mfma_f32_16x16x32_bf16(A, B, C, 0, 0, 0)

// async global->LDS, 16B per lane: dest = (wave-uniform base) + lane*16
#define GLOAD16(gp, lp)                                          \
  __builtin_amdgcn_global_load_lds(                              \
      (const __attribute__((address_space(1))) void*)(gp),       \
      (__attribute__((address_space(3))) void*)(lp), 16, 0, 0)

// 2^x (v_exp_f32 computes 2^S0)
__device__ __forceinline__ float fexp2(float x) {
#if __has_builtin(__builtin_amdgcn_exp2f)
  return __builtin_amdgcn_exp2f(x);
#else
  float r;
  asm("v_exp_f32 %0, %1" : "=v"(r) : "v"(x));
  return r;
#endif
}

// Q pre-scale: scores = (q.k)/sqrt(64) in log2 units for exp2-softmax
#define QSCL 0.18033688011112042f  // 0.125 * log2(e)

// ---------------------------------------------------------------------------
// All weight transposes in ONE launch (fp32 -> bf16)
// ---------------------------------------------------------------------------
__global__ __launch_bounds__(256) void transpose_all_kernel(
    const float* __restrict__ w0, const float* __restrict__ w1,
    const float* __restrict__ w2, const float* __restrict__ w3,
    bf16* __restrict__ out4,
    const float* __restrict__ W1, bf16* __restrict__ w1t,
    const float* __restrict__ W2, bf16* __restrict__ w2t)
{
  __shared__ float tile[32][33];
  const int bid = blockIdx.x;
  const float* in;
  bf16* out;
  int K, N, kt, nt;
  if (bid < 4096) {
    const float* srcs[4] = {w0, w1, w2, w3};
    in = srcs[bid >> 10];
    out = out4 + (size_t)(bid >> 10) * 1024 * 1024;
    K = 1024; N = 1024;
    const int t = bid & 1023;
    nt = (t & 31) * 32; kt = (t >> 5) * 32;
  } else if (bid < 8192) {
    in = W1; out = w1t; K = 1024; N = 4096;
    const int t = bid - 4096;
    nt = (t & 127) * 32; kt = (t >> 7) * 32;
  } else {
    in = W2; out = w2t; K = 4096; N = 1024;
    const int t = bid - 8192;
    nt = (t & 31) * 32; kt = (t >> 5) * 32;
  }
  const int tx = threadIdx.x, ty = threadIdx.y;
#pragma unroll
  for (int j = 0; j < 4; ++j)
    tile[ty + j * 8][tx] = in[(size_t)(kt + ty + j * 8) * N + nt + tx];
  __syncthreads();
#pragma unroll
  for (int j = 0; j < 4; ++j)
    out[(size_t)(nt + ty + j * 8) * K + kt + tx] = (bf16)tile[tx][ty + j * 8];
}

// ---------------------------------------------------------------------------
// LayerNorm (eps=1e-3), fp32 in -> bf16 out. One block per row of 1024.
// ---------------------------------------------------------------------------
__global__ __launch_bounds__(256) void ln_kernel(
    const float* __restrict__ in, const float* __restrict__ gamma,
    const float* __restrict__ beta, bf16* __restrict__ out)
{
  const int row = blockIdx.x;
  const int t = threadIdx.x;
  const float4 v = ((const float4*)(in + (size_t)row * 1024))[t];
  float s = v.x + v.y + v.z + v.w;
  float sq = v.x * v.x + v.y * v.y + v.z * v.z + v.w * v.w;
#pragma unroll
  for (int m = 1; m < 64; m <<= 1) {
    s += __shfl_xor(s, m);
    sq += __shfl_xor(sq, m);
  }
  __shared__ float ssum[4], ssq[4];
  const int w = t >> 6;
  if ((t & 63) == 0) { ssum[w] = s; ssq[w] = sq; }
  __syncthreads();
  s = ssum[0] + ssum[1] + ssum[2] + ssum[3];
  sq = ssq[0] + ssq[1] + ssq[2] + ssq[3];
  const float mu = s * (1.0f / 1024.0f);
  const float var = sq * (1.0f / 1024.0f) - mu * mu;
  const float rs = rsqrtf(var + 1e-3f);
  const float4 g = ((const float4*)gamma)[t];
  const float4 b = ((const float4*)beta)[t];
  bf16x4 o;
  o[0] = (bf16)((v.x - mu) * rs * g.x + b.x);
  o[1] = (bf16)((v.y - mu) * rs * g.y + b.y);
  o[2] = (bf16)((v.z - mu) * rs * g.z + b.z);
  o[3] = (bf16)((v.w - mu) * rs * g.w + b.w);
  *(bf16x4*)(out + (size_t)row * 1024 + t * 4) = o;
}

// LayerNorm, bf16 in -> bf16 out (for the bf16 x2 chain)
__global__ __launch_bounds__(256) void ln_b_kernel(
    const bf16* __restrict__ in, const float* __restrict__ gamma,
    const float* __restrict__ beta, bf16* __restrict__ out)
{
  const int row = blockIdx.x;
  const int t = threadIdx.x;
  const bf16x4 vb = *(const bf16x4*)(in + (size_t)row * 1024 + t * 4);
  float v0 = (float)vb[0], v1 = (float)vb[1], v2 = (float)vb[2], v3 = (float)vb[3];
  float s = v0 + v1 + v2 + v3;
  float sq = v0 * v0 + v1 * v1 + v2 * v2 + v3 * v3;
#pragma unroll
  for (int m = 1; m < 64; m <<= 1) {
    s += __shfl_xor(s, m);
    sq += __shfl_xor(sq, m);
  }
  __shared__ float ssum[4], ssq[4];
  const int w = t >> 6;
  if ((t & 63) == 0) { ssum[w] = s; ssq[w] = sq; }
  __syncthreads();
  s = ssum[0] + ssum[1] + ssum[2] + ssum[3];
  sq = ssq[0] + ssq[1] + ssq[2] + ssq[3];
  const float mu = s * (1.0f / 1024.0f);
  const float var = sq * (1.0f / 1024.0f) - mu * mu;
  const float rs = rsqrtf(var + 1e-3f);
  const float4 g = ((const float4*)gamma)[t];
  const float4 b = ((const float4*)beta)[t];
  bf16x4 o;
  o[0] = (bf16)((v0 - mu) * rs * g.x + b.x);
  o[1] = (bf16)((v1 - mu) * rs * g.y + b.y);
  o[2] = (bf16)((v2 - mu) * rs * g.z + b.z);
  o[3] = (bf16)((v3 - mu) * rs * g.w + b.w);
  *(bf16x4*)(out + (size_t)row * 1024 + t * 4) = o;
}

// ---------------------------------------------------------------------------
// GEMM: C[M,N] = epilogue(A[M,K] @ Bt[N,K]^T + bias)   (r14-proven)
// ---------------------------------------------------------------------------
template <int BM, int BN, int BK, int EPI, int SWZ>
__global__ __launch_bounds__(256, 2) void gemm_bt(
    const bf16* __restrict__ A, const bf16* __restrict__ Bt,
    const float* __restrict__ bias0, const float* __restrict__ bias1,
    const float* __restrict__ bias2, const float* __restrict__ resid,
    const bf16* __restrict__ residb,
    bf16* __restrict__ out0, bf16* __restrict__ out1, bf16* __restrict__ out2,
    float* __restrict__ outf, int M, int N, int K)
{
  constexpr int WM = BM / 2, WN = BN / 2;
  constexpr int MI = WM / 16, NJ = WN / 16;
  constexpr int KK = BK / 32;
  constexpr int NSLOT = BK / 8;
  constexpr int SMASK = NSLOT - 1;
  constexpr int RPL = 512 / BK;             // rows per gload16
  constexpr int ALOADS = BM / (4 * RPL);
  constexpr int BLOADS = BN / (4 * RPL);
  constexpr int S = ALOADS + BLOADS;

  __shared__ bf16 As[3][BM * BK];
  __shared__ bf16 Bs[3][BN * BK];
  const int tid = threadIdx.x;
  const int lane = tid & 63, w = tid >> 6;
  const int wr = w >> 1, wc = w & 1;
  const int g = lane >> 4, lr = lane & 15;

  int bx = blockIdx.x, by = blockIdx.y;
  if constexpr (SWZ) {  // XCD by-chunking
    const int bid = bx + gridDim.x * by;
    const int xcd = bid & 7, idx = bid >> 3;
    const int chunk = gridDim.y >> 3;
    by = xcd * chunk + (idx % chunk);
    bx = idx / chunk;
  }
  const int brow = by * BM, bcol = bx * BN;

  f32x4 acc[MI][NJ] = {};

  const int lrow = lane / NSLOT;
  const int slot = lane & SMASK;
  int lcol;
  if constexpr (BK == 32)
    lcol = ((slot - (lrow >> 1)) & 3) * 8;  // rotation involution
  else
    lcol = (slot ^ (lrow & 7)) * 8;         // XOR

  auto stage = [&](int buf, int k0) {
#pragma unroll
    for (int j = 0; j < ALOADS; ++j) {
      const int row0 = w * (BM / 4) + j * RPL;
      GLOAD16(A + (size_t)(brow + row0 + lrow) * K + k0 + lcol,
              &As[buf][row0 * BK]);
    }
#pragma unroll
    for (int j = 0; j < BLOADS; ++j) {
      const int row0 = w * (BN / 4) + j * RPL;
      GLOAD16(Bt + (size_t)(bcol + row0 + lrow) * K + k0 + lcol,
              &Bs[buf][row0 * BK]);
    }
  };

  auto rdslot = [&](int kg) {
    if constexpr (BK == 32) return ((kg + (lr >> 1)) & 3) * 8;
    else return (kg ^ (lr & 7)) * 8;
  };

  const int nk = K / BK;
  stage(0, 0);
  stage(1, BK);
  int cur = 0;
  for (int t = 0; t < nk; ++t) {
    if (t + 1 < nk) {
      if constexpr (S == 3)
        asm volatile("s_waitcnt vmcnt(3)" ::: "memory");
      else if constexpr (S == 4)
        asm volatile("s_waitcnt vmcnt(4)" ::: "memory");
      else
        asm volatile("s_waitcnt vmcnt(6)" ::: "memory");
    } else {
      asm volatile("s_waitcnt vmcnt(0)" ::: "memory");
    }
    __builtin_amdgcn_s_barrier();
    __builtin_amdgcn_sched_barrier(0);

    bf16x8 afr[MI][KK], bfr[NJ][KK];
#pragma unroll
    for (int i = 0; i < MI; ++i)
#pragma unroll
      for (int kk = 0; kk < KK; ++kk)
        afr[i][kk] = *(const bf16x8*)&As[cur][(wr * WM + i * 16 + lr) * BK +
                                             rdslot(kk * 4 + g)];
#pragma unroll
    for (int j = 0; j < NJ; ++j)
#pragma unroll
      for (int kk = 0; kk < KK; ++kk)
        bfr[j][kk] = *(const bf16x8*)&Bs[cur][(wc * WN + j * 16 + lr) * BK +
                                             rdslot(kk * 4 + g)];

    if (t + 2 < nk) {
      int nb = cur + 2;
      if (nb >= 3) nb -= 3;
      stage(nb, (t + 2) * BK);
    }

    __builtin_amdgcn_s_setprio(1);
#pragma unroll
    for (int kk = 0; kk < KK; ++kk)
#pragma unroll
      for (int i = 0; i < MI; ++i)
#pragma unroll
        for (int j = 0; j < NJ; ++j)
          acc[i][j] = MFMA16(afr[i][kk], bfr[j][kk], acc[i][j]);
    __builtin_amdgcn_s_setprio(0);

    ++cur;
    if (cur == 3) cur = 0;
  }

#pragma unroll
  for (int i = 0; i < MI; ++i) {
#pragma unroll
    for (int j = 0; j < NJ; ++j) {
      const int r0 = brow + wr * WM + i * 16 + g * 4;
      const int c = bcol + wc * WN + j * 16 + lr;
      if constexpr (EPI == 1) {
        const float bv = bias0[c];
#pragma unroll
        for (int rr = 0; rr < 4; ++rr)
          out0[(size_t)(r0 + rr) * N + c] =
              (bf16)fmaxf(acc[i][j][rr] + bv, 0.0f);
      } else if constexpr (EPI == 5) {
        const float bv = bias0[c];
#pragma unroll
        for (int rr = 0; rr < 4; ++rr) {
          const size_t idx = (size_t)(r0 + rr) * N + c;
          out0[idx] = (bf16)(acc[i][j][rr] + bv + resid[idx]);
        }
      } else if constexpr (EPI == 6) {
        const float bv = bias0[c];
#pragma unroll
        for (int rr = 0; rr < 4; ++rr) {
          const size_t idx = (size_t)(r0 + rr) * N + c;
          outf[idx] = acc[i][j][rr] + bv + (float)residb[idx];
        }
      } else {  // EPI 4: fused QKV
        const int sub = c >> 10;
        const int c1 = c & 1023;
        if (sub == 0) {
          const float bv = bias0[c1];
#pragma unroll
          for (int rr = 0; rr < 4; ++rr)
            out0[(size_t)(r0 + rr) * 1024 + c1] =
                (bf16)((acc[i][j][rr] + bv) * QSCL);
        } else if (sub == 1) {
          const float bv = bias1[c1];
#pragma unroll
          for (int rr = 0; rr < 4; ++rr)
            out1[(size_t)(r0 + rr) * 1024 + c1] = (bf16)(acc[i][j][rr] + bv);
        } else {
          const float bv = bias2[c1];
          const int bb = r0 >> 11, t0 = r0 & 2047;
          const int hh = c1 >> 6, dd = c1 & 63;
          bf16x4 pk;
#pragma unroll
          for (int rr = 0; rr < 4; ++rr) pk[rr] = (bf16)(acc[i][j][rr] + bv);
          *(bf16x4*)(out2 + ((size_t)((bb * 16 + hh) * 64 + dd)) * 2048 + t0) = pk;
        }
      }
    }
  }
}

// ---------------------------------------------------------------------------
// Causal flash attention v7: BARRIER-FREE per-wave jobs.
// Each wave owns 16 q-rows; K and V^T fragments loaded DIRECTLY from global
// (fragment pattern = 16 rows x 64B, wave-coalesced, L2-served). P stays in
// per-wave LDS (same-wave lgkm dep). Zero __syncthreads; waves independent.
// Block bid: a=bid>>5, bh=bid&31; jobs {a, 127-a, 63-a, 64+a} (qt16 units of
// 16 rows) rotated across waves by bid>>8 -> per-block sum ~const, per-SIMD
// long/short mixed. Same-bh blocks share one XCD (bid mod 8) -> K/V L2-local.
// ---------------------------------------------------------------------------
__global__ __launch_bounds__(256) void attn_kernel(
    const bf16* __restrict__ q, const bf16* __restrict__ kmat,
    const bf16* __restrict__ vt, bf16* __restrict__ ctx)
{
  __shared__ bf16 Pq[4][16][88];
  const int bid = blockIdx.x;
  const int a = bid >> 5;
  const int bh = bid & 31;
  const int b_ = bh >> 4, h_ = bh & 15;
  const int tid = threadIdx.x;
  const int lane = tid & 63, w = tid >> 6;
  const int g = lane >> 4, lr = lane & 15;

  const int p = (w + (bid >> 8)) & 3;  // rotate job->wave per co-resident set
  const int qt16 = (p == 0) ? a : (p == 1) ? (127 - a)
                 : (p == 2) ? (63 - a) : (64 + a);
  const int q0 = qt16 * 16;
  const int qrow = q0 + lr;  // this lane's q row (S^T layout)

  bf16x8 qf[2];
  {
    const bf16* qp = q + (size_t)(b_ * 2048 + qrow) * 1024 + h_ * 64 + g * 8;
    qf[0] = *(const bf16x8*)qp;
    qf[1] = *(const bf16x8*)(qp + 32);
  }

  f32x4 o[4] = {};
  float l = 0.f;

  const bf16* kbase = kmat + (size_t)(b_ * 2048) * 1024 + h_ * 64;
  const bf16* vbase = vt + (size_t)(b_ * 16 + h_) * 64 * 2048;

  const int ns = (qt16 >> 2) + 1;  // 64-wide s-tiles
  for (int t = 0; t < ns; ++t) {
    const int s0 = t << 6;

    // K fragments direct from global: ak[n][kk] = K[s0+n*16+lr][kk*32+g*8..]
    bf16x8 ak[4][2];
#pragma unroll
    for (int n = 0; n < 4; ++n) {
      const bf16* kp = kbase + (size_t)(s0 + n * 16 + lr) * 1024 + g * 8;
      ak[n][0] = *(const bf16x8*)kp;
      ak[n][1] = *(const bf16x8*)(kp + 32);
    }

    f32x4 st[4];
    __builtin_amdgcn_s_setprio(1);
#pragma unroll
    for (int n = 0; n < 4; ++n) {
      f32x4 z = {};
      z = MFMA16(ak[n][0], qf[0], z);
      z = MFMA16(ak[n][1], qf[1], z);
      st[n] = z;
    }
    __builtin_amdgcn_s_setprio(0);

    // V fragments direct from global (latency hides under exp2/P roundtrip)
    bf16x8 bv[4][2];
#pragma unroll
    for (int n = 0; n < 4; ++n) {
      const bf16* vp = vbase + (size_t)(n * 16 + lr) * 2048 + s0 + g * 8;
      bv[n][0] = *(const bf16x8*)vp;
      bv[n][1] = *(const bf16x8*)(vp + 32);
    }

    if (t == ns - 1) {  // causal mask on the diagonal tile
#pragma unroll
      for (int n = 0; n < 4; ++n)
#pragma unroll
        for (int r = 0; r < 4; ++r)
          if (s0 + n * 16 + g * 4 + r > qrow) st[n][r] = -1e30f;
    }

    float rs = 0.f;
#pragma unroll
    for (int n = 0; n < 4; ++n) {
      bf16x4 pk;
#pragma unroll
      for (int r = 0; r < 4; ++r) {
        const float pv = fexp2(st[n][r]);
        rs += pv;
        pk[r] = (bf16)pv;
      }
      *(bf16x4*)&Pq[w][lr][n * 16 + g * 4] = pk;
    }

    bf16x8 pa[2];
#pragma unroll
    for (int kk = 0; kk < 2; ++kk)
      pa[kk] = *(const bf16x8*)&Pq[w][lr][kk * 32 + g * 8];
    __builtin_amdgcn_s_setprio(1);
#pragma unroll
    for (int n = 0; n < 4; ++n) {
      o[n] = MFMA16(pa[0], bv[n][0], o[n]);
      o[n] = MFMA16(pa[1], bv[n][1], o[n]);
    }
    __builtin_amdgcn_s_setprio(0);

    rs += __shfl_xor(rs, 16);
    rs += __shfl_xor(rs, 32);
    l += rs;
  }

  float lq[4];
#pragma unroll
  for (int r = 0; r < 4; ++r) lq[r] = __shfl(l, g * 4 + r);
#pragma unroll
  for (int r = 0; r < 4; ++r) {
    const float inv = 1.0f / lq[r];
#pragma unroll
    for (int n = 0; n < 4; ++n)
      ctx[(size_t)(b_ * 2048 + q0 + g * 4 + r) * 1024 + h_ * 64 + n * 16 + lr] =
          (bf16)(o[n][r] * inv);
  }
}

// ---------------------------------------------------------------------------
extern "C" void kernel_launch(void* const* d_in, const int* in_sizes, int n_in,
                              void* d_out, int out_size, void* d_ws, size_t ws_size,
                              hipStream_t stream)
{
  (void)in_sizes; (void)n_in; (void)out_size; (void)ws_size;
  const float* x   = (const float*)d_in[0];
  const float* Wq  = (const float*)d_in[1];
  const float* bq  = (const float*)d_in[2];
  const float* Wk  = (const float*)d_in[3];
  const float* bk  = (const float*)d_in[4];
  const float* Wv  = (const float*)d_in[5];
  const float* bv  = (const float*)d_in[6];
  const float* Wo  = (const float*)d_in[7];
  const float* bo  = (const float*)d_in[8];
  const float* W1  = (const float*)d_in[9];
  const float* b1  = (const float*)d_in[10];
  const float* W2  = (const float*)d_in[11];
  const float* b2  = (const float*)d_in[12];
  const float* g1  = (const float*)d_in[13];
  const float* be1 = (const float*)d_in[14];
  const float* g2  = (const float*)d_in[15];
  const float* be2 = (const float*)d_in[16];
  float* out = (float*)d_out;

  char* ws = (char*)d_ws;
  const size_t MB = 1024 * 1024;
  bf16* wqkv_t = (bf16*)(ws + 0 * MB);  // [3072][1024]: wq|wk|wv contiguous
  bf16* wo_t = (bf16*)(ws + 6 * MB);
  bf16* w1_t = (bf16*)(ws + 8 * MB);   // [4096][1024]
  bf16* w2_t = (bf16*)(ws + 16 * MB);  // [1024][4096]
  bf16* h1   = (bf16*)(ws + 24 * MB);  // [4096][1024]
  bf16* qbuf = (bf16*)(ws + 32 * MB);  // [4096][1024]
  bf16* kbuf = (bf16*)(ws + 40 * MB);  // [4096][1024]
  bf16* vtb  = (bf16*)(ws + 48 * MB);  // [2][16][64][2048]
  bf16* ctx  = (bf16*)(ws + 56 * MB);  // [4096][1024]
  bf16* h2   = (bf16*)(ws + 64 * MB);  // [4096][1024]
  bf16* x2b  = (bf16*)(ws + 72 * MB);  // [4096][1024] bf16 x2
  bf16* ff1  = (bf16*)(ws + 24 * MB);  // [4096][4096], overlays h1/q/k/vtb (dead)

  // all weight transposes in one launch (12288 tiles)
  transpose_all_kernel<<<12288, dim3(32, 8), 0, stream>>>(
      Wq, Wk, Wv, Wo, wqkv_t, W1, w1_t, W2, w2_t);

  ln_kernel<<<4096, 256, 0, stream>>>(x, g1, be1, h1);

  // fused QKV: -> q(prescaled), k, v(transposed)   [128x128, BK=32, 3/CU]
  gemm_bt<128, 128, 32, 4, 0><<<dim3(24, 32), 256, 0, stream>>>(
      h1, wqkv_t, bq, bk, bv, nullptr, nullptr, qbuf, kbuf, vtb, nullptr,
      4096, 3072, 1024);

  // barrier-free per-wave attention: 1024 blocks x 4 independent wave-jobs
  attn_kernel<<<1024, 256, 0, stream>>>(qbuf, kbuf, vtb, ctx);

  // x2 = x + ctx@Wo + bo -> bf16 x2b   [128x64, BK=64, 2/CU, EPI 5]
  gemm_bt<128, 64, 64, 5, 0><<<dim3(16, 32), 256, 0, stream>>>(
      ctx, wo_t, bo, nullptr, nullptr, x, nullptr, x2b, nullptr, nullptr,
      nullptr, 4096, 1024, 1024);

  ln_b_kernel<<<4096, 256, 0, stream>>>(x2b, g2, be2, h2);

  // ff1 = relu(h2 @ W1 + b1)   [256x128, BK=32, 2/CU, 32 MFMA/iter]
  gemm_bt<256, 128, 32, 1, 0><<<dim3(32, 16), 256, 0, stream>>>(
      h2, w1_t, b1, nullptr, nullptr, nullptr, nullptr, ff1, nullptr, nullptr,
      nullptr, 4096, 4096, 1024);

  // out = x2b + ff1@W2 + b2 -> d_out (f32)  [128x64, BK=64, XCD swz, EPI 6]
  gemm_bt<128, 64, 64, 6, 1><<<dim3(16, 32), 256, 0, stream>>>(
      ff1, w2_t, b2, nullptr, nullptr, nullptr, x2b, nullptr, nullptr, nullptr,
      out, 4096, 1024, 4096);
}

// Round 16
// 196.749 us; speedup vs baseline: 1.4075x; 1.4075x over previous
//
#include <hip/hip_runtime.h>

typedef __bf16 bf16;
typedef __attribute__((ext_vector_type(8))) __bf16 bf16x8;
typedef __attribute__((ext_vector_type(4))) __bf16 bf16x4;
typedef __attribute__((ext_vector_type(4))) float f32x4;

#define MFMA16(A, B, C) __builtin_amdgcn_mfma_f32_16x16x32_bf16(A, B, C, 0, 0, 0)

// async global->LDS, 16B per lane: dest = (wave-uniform base) + lane*16
#define GLOAD16(gp, lp)                                          \
  __builtin_amdgcn_global_load_lds(                              \
      (const __attribute__((address_space(1))) void*)(gp),       \
      (__attribute__((address_space(3))) void*)(lp), 16, 0, 0)

// 2^x (v_exp_f32 computes 2^S0)
__device__ __forceinline__ float fexp2(float x) {
#if __has_builtin(__builtin_amdgcn_exp2f)
  return __builtin_amdgcn_exp2f(x);
#else
  float r;
  asm("v_exp_f32 %0, %1" : "=v"(r) : "v"(x));
  return r;
#endif
}

// Q pre-scale: scores = (q.k)/sqrt(64) in log2 units for exp2-softmax
#define QSCL 0.18033688011112042f  // 0.125 * log2(e)

// ---------------------------------------------------------------------------
// All weight transposes in ONE launch (fp32 -> bf16)
// ---------------------------------------------------------------------------
__global__ __launch_bounds__(256) void transpose_all_kernel(
    const float* __restrict__ w0, const float* __restrict__ w1,
    const float* __restrict__ w2, const float* __restrict__ w3,
    bf16* __restrict__ out4,
    const float* __restrict__ W1, bf16* __restrict__ w1t,
    const float* __restrict__ W2, bf16* __restrict__ w2t)
{
  __shared__ float tile[32][33];
  const int bid = blockIdx.x;
  const float* in;
  bf16* out;
  int K, N, kt, nt;
  if (bid < 4096) {
    const float* srcs[4] = {w0, w1, w2, w3};
    in = srcs[bid >> 10];
    out = out4 + (size_t)(bid >> 10) * 1024 * 1024;
    K = 1024; N = 1024;
    const int t = bid & 1023;
    nt = (t & 31) * 32; kt = (t >> 5) * 32;
  } else if (bid < 8192) {
    in = W1; out = w1t; K = 1024; N = 4096;
    const int t = bid - 4096;
    nt = (t & 127) * 32; kt = (t >> 7) * 32;
  } else {
    in = W2; out = w2t; K = 4096; N = 1024;
    const int t = bid - 8192;
    nt = (t & 31) * 32; kt = (t >> 5) * 32;
  }
  const int tx = threadIdx.x, ty = threadIdx.y;
#pragma unroll
  for (int j = 0; j < 4; ++j)
    tile[ty + j * 8][tx] = in[(size_t)(kt + ty + j * 8) * N + nt + tx];
  __syncthreads();
#pragma unroll
  for (int j = 0; j < 4; ++j)
    out[(size_t)(nt + ty + j * 8) * K + kt + tx] = (bf16)tile[tx][ty + j * 8];
}

// ---------------------------------------------------------------------------
// LayerNorm (eps=1e-3), fp32 in -> bf16 out. One block per row of 1024.
// ---------------------------------------------------------------------------
__global__ __launch_bounds__(256) void ln_kernel(
    const float* __restrict__ in, const float* __restrict__ gamma,
    const float* __restrict__ beta, bf16* __restrict__ out)
{
  const int row = blockIdx.x;
  const int t = threadIdx.x;
  const float4 v = ((const float4*)(in + (size_t)row * 1024))[t];
  float s = v.x + v.y + v.z + v.w;
  float sq = v.x * v.x + v.y * v.y + v.z * v.z + v.w * v.w;
#pragma unroll
  for (int m = 1; m < 64; m <<= 1) {
    s += __shfl_xor(s, m);
    sq += __shfl_xor(sq, m);
  }
  __shared__ float ssum[4], ssq[4];
  const int w = t >> 6;
  if ((t & 63) == 0) { ssum[w] = s; ssq[w] = sq; }
  __syncthreads();
  s = ssum[0] + ssum[1] + ssum[2] + ssum[3];
  sq = ssq[0] + ssq[1] + ssq[2] + ssq[3];
  const float mu = s * (1.0f / 1024.0f);
  const float var = sq * (1.0f / 1024.0f) - mu * mu;
  const float rs = rsqrtf(var + 1e-3f);
  const float4 g = ((const float4*)gamma)[t];
  const float4 b = ((const float4*)beta)[t];
  bf16x4 o;
  o[0] = (bf16)((v.x - mu) * rs * g.x + b.x);
  o[1] = (bf16)((v.y - mu) * rs * g.y + b.y);
  o[2] = (bf16)((v.z - mu) * rs * g.z + b.z);
  o[3] = (bf16)((v.w - mu) * rs * g.w + b.w);
  *(bf16x4*)(out + (size_t)row * 1024 + t * 4) = o;
}

// LayerNorm, bf16 in -> bf16 out (for the bf16 x2 chain)
__global__ __launch_bounds__(256) void ln_b_kernel(
    const bf16* __restrict__ in, const float* __restrict__ gamma,
    const float* __restrict__ beta, bf16* __restrict__ out)
{
  const int row = blockIdx.x;
  const int t = threadIdx.x;
  const bf16x4 vb = *(const bf16x4*)(in + (size_t)row * 1024 + t * 4);
  float v0 = (float)vb[0], v1 = (float)vb[1], v2 = (float)vb[2], v3 = (float)vb[3];
  float s = v0 + v1 + v2 + v3;
  float sq = v0 * v0 + v1 * v1 + v2 * v2 + v3 * v3;
#pragma unroll
  for (int m = 1; m < 64; m <<= 1) {
    s += __shfl_xor(s, m);
    sq += __shfl_xor(sq, m);
  }
  __shared__ float ssum[4], ssq[4];
  const int w = t >> 6;
  if ((t & 63) == 0) { ssum[w] = s; ssq[w] = sq; }
  __syncthreads();
  s = ssum[0] + ssum[1] + ssum[2] + ssum[3];
  sq = ssq[0] + ssq[1] + ssq[2] + ssq[3];
  const float mu = s * (1.0f / 1024.0f);
  const float var = sq * (1.0f / 1024.0f) - mu * mu;
  const float rs = rsqrtf(var + 1e-3f);
  const float4 g = ((const float4*)gamma)[t];
  const float4 b = ((const float4*)beta)[t];
  bf16x4 o;
  o[0] = (bf16)((v0 - mu) * rs * g.x + b.x);
  o[1] = (bf16)((v1 - mu) * rs * g.y + b.y);
  o[2] = (bf16)((v2 - mu) * rs * g.z + b.z);
  o[3] = (bf16)((v3 - mu) * rs * g.w + b.w);
  *(bf16x4*)(out + (size_t)row * 1024 + t * 4) = o;
}

// ---------------------------------------------------------------------------
// GEMM: C[M,N] = epilogue(A[M,K] @ Bt[N,K]^T + bias)
// 3 LDS buffers, prefetch distance 2 via global_load_lds, counted vmcnt,
// raw s_barrier, T5 setprio, both-sides swizzle (XOR @BK64, ROT @BK32).
// SWZ=1: XCD by-chunk grid remap (localize A panels per XCD L2).
// EPI 1: bf16 relu            EPI 4: fused QKV epilogue
// EPI 5: bf16 out = acc+bias+resid(f32)     (O-proj -> x2 bf16)
// EPI 6: f32 out = acc+bias+residb(bf16)    (FF2 -> d_out)
// ---------------------------------------------------------------------------
template <int BM, int BN, int BK, int EPI, int SWZ>
__global__ __launch_bounds__(256, 2) void gemm_bt(
    const bf16* __restrict__ A, const bf16* __restrict__ Bt,
    const float* __restrict__ bias0, const float* __restrict__ bias1,
    const float* __restrict__ bias2, const float* __restrict__ resid,
    const bf16* __restrict__ residb,
    bf16* __restrict__ out0, bf16* __restrict__ out1, bf16* __restrict__ out2,
    float* __restrict__ outf, int M, int N, int K)
{
  constexpr int WM = BM / 2, WN = BN / 2;
  constexpr int MI = WM / 16, NJ = WN / 16;
  constexpr int KK = BK / 32;
  constexpr int NSLOT = BK / 8;
  constexpr int SMASK = NSLOT - 1;
  constexpr int RPL = 512 / BK;             // rows per gload16
  constexpr int ALOADS = BM / (4 * RPL);
  constexpr int BLOADS = BN / (4 * RPL);
  constexpr int S = ALOADS + BLOADS;

  __shared__ bf16 As[3][BM * BK];
  __shared__ bf16 Bs[3][BN * BK];
  const int tid = threadIdx.x;
  const int lane = tid & 63, w = tid >> 6;
  const int wr = w >> 1, wc = w & 1;
  const int g = lane >> 4, lr = lane & 15;

  int bx = blockIdx.x, by = blockIdx.y;
  if constexpr (SWZ) {  // XCD by-chunking: each XCD owns a contiguous by range
    const int bid = bx + gridDim.x * by;
    const int xcd = bid & 7, idx = bid >> 3;
    const int chunk = gridDim.y >> 3;
    by = xcd * chunk + (idx % chunk);
    bx = idx / chunk;
  }
  const int brow = by * BM, bcol = bx * BN;

  f32x4 acc[MI][NJ] = {};

  const int lrow = lane / NSLOT;            // row within a gload group
  const int slot = lane & SMASK;            // linear LDS 16B slot
  int lcol;
  if constexpr (BK == 32)
    lcol = ((slot - (lrow >> 1)) & 3) * 8;  // rotation involution
  else
    lcol = (slot ^ (lrow & 7)) * 8;         // XOR

  auto stage = [&](int buf, int k0) {
#pragma unroll
    for (int j = 0; j < ALOADS; ++j) {
      const int row0 = w * (BM / 4) + j * RPL;
      GLOAD16(A + (size_t)(brow + row0 + lrow) * K + k0 + lcol,
              &As[buf][row0 * BK]);
    }
#pragma unroll
    for (int j = 0; j < BLOADS; ++j) {
      const int row0 = w * (BN / 4) + j * RPL;
      GLOAD16(Bt + (size_t)(bcol + row0 + lrow) * K + k0 + lcol,
              &Bs[buf][row0 * BK]);
    }
  };

  auto rdslot = [&](int kg) {  // swizzled 16B-slot index for k-group kg
    if constexpr (BK == 32) return ((kg + (lr >> 1)) & 3) * 8;
    else return (kg ^ (lr & 7)) * 8;
  };

  const int nk = K / BK;
  stage(0, 0);
  stage(1, BK);
  int cur = 0;
  for (int t = 0; t < nk; ++t) {
    if (t + 1 < nk) {
      if constexpr (S == 3)
        asm volatile("s_waitcnt vmcnt(3)" ::: "memory");
      else if constexpr (S == 4)
        asm volatile("s_waitcnt vmcnt(4)" ::: "memory");
      else
        asm volatile("s_waitcnt vmcnt(6)" ::: "memory");
    } else {
      asm volatile("s_waitcnt vmcnt(0)" ::: "memory");
    }
    __builtin_amdgcn_s_barrier();
    __builtin_amdgcn_sched_barrier(0);

    bf16x8 afr[MI][KK], bfr[NJ][KK];
#pragma unroll
    for (int i = 0; i < MI; ++i)
#pragma unroll
      for (int kk = 0; kk < KK; ++kk)
        afr[i][kk] = *(const bf16x8*)&As[cur][(wr * WM + i * 16 + lr) * BK +
                                             rdslot(kk * 4 + g)];
#pragma unroll
    for (int j = 0; j < NJ; ++j)
#pragma unroll
      for (int kk = 0; kk < KK; ++kk)
        bfr[j][kk] = *(const bf16x8*)&Bs[cur][(wc * WN + j * 16 + lr) * BK +
                                             rdslot(kk * 4 + g)];

    if (t + 2 < nk) {
      int nb = cur + 2;
      if (nb >= 3) nb -= 3;
      stage(nb, (t + 2) * BK);
    }

    __builtin_amdgcn_s_setprio(1);
#pragma unroll
    for (int kk = 0; kk < KK; ++kk)
#pragma unroll
      for (int i = 0; i < MI; ++i)
#pragma unroll
        for (int j = 0; j < NJ; ++j)
          acc[i][j] = MFMA16(afr[i][kk], bfr[j][kk], acc[i][j]);
    __builtin_amdgcn_s_setprio(0);

    ++cur;
    if (cur == 3) cur = 0;
  }

#pragma unroll
  for (int i = 0; i < MI; ++i) {
#pragma unroll
    for (int j = 0; j < NJ; ++j) {
      const int r0 = brow + wr * WM + i * 16 + g * 4;
      const int c = bcol + wc * WN + j * 16 + lr;
      if constexpr (EPI == 1) {
        const float bv = bias0[c];
#pragma unroll
        for (int rr = 0; rr < 4; ++rr)
          out0[(size_t)(r0 + rr) * N + c] =
              (bf16)fmaxf(acc[i][j][rr] + bv, 0.0f);
      } else if constexpr (EPI == 5) {
        const float bv = bias0[c];
#pragma unroll
        for (int rr = 0; rr < 4; ++rr) {
          const size_t idx = (size_t)(r0 + rr) * N + c;
          out0[idx] = (bf16)(acc[i][j][rr] + bv + resid[idx]);
        }
      } else if constexpr (EPI == 6) {
        const float bv = bias0[c];
#pragma unroll
        for (int rr = 0; rr < 4; ++rr) {
          const size_t idx = (size_t)(r0 + rr) * N + c;
          outf[idx] = acc[i][j][rr] + bv + (float)residb[idx];
        }
      } else {  // EPI 4: fused QKV
        const int sub = c >> 10;
        const int c1 = c & 1023;
        if (sub == 0) {  // Q, pre-scaled into log2-softmax units
          const float bv = bias0[c1];
#pragma unroll
          for (int rr = 0; rr < 4; ++rr)
            out0[(size_t)(r0 + rr) * 1024 + c1] =
                (bf16)((acc[i][j][rr] + bv) * QSCL);
        } else if (sub == 1) {
          const float bv = bias1[c1];
#pragma unroll
          for (int rr = 0; rr < 4; ++rr)
            out1[(size_t)(r0 + rr) * 1024 + c1] = (bf16)(acc[i][j][rr] + bv);
        } else {
          const float bv = bias2[c1];
          const int bb = r0 >> 11, t0 = r0 & 2047;
          const int hh = c1 >> 6, dd = c1 & 63;
          bf16x4 pk;
#pragma unroll
          for (int rr = 0; rr < 4; ++rr) pk[rr] = (bf16)(acc[i][j][rr] + bv);
          *(bf16x4*)(out2 + ((size_t)((bb * 16 + hh) * 64 + dd)) * 2048 + t0) = pk;
        }
      }
    }
  }
}

// ---------------------------------------------------------------------------
// Causal flash attention, S^T formulation, exp2-softmax (no max-tracking).
// r12/r14-proven body: k4-balanced qt map, 64-s tiles, XOR-swizzled K/V LDS,
// reg-prefetch across barrier, T5 setprio, overlapped l-reduce.
// This structure's empirical plateau ~44 us (5 structural variants tested).
// ---------------------------------------------------------------------------
__global__ __launch_bounds__(256) void attn_kernel(
    const bf16* __restrict__ q, const bf16* __restrict__ kmat,
    const bf16* __restrict__ vt, bf16* __restrict__ ctx)
{
  __shared__ bf16 Ks[64 * 64];
  __shared__ bf16 Vs[64 * 64];
  __shared__ bf16 Pq[4][16][88];
  const int bx = blockIdx.x, by = blockIdx.y;
  const int k4 = by >> 3;
  const int qt = (k4 == 0) ? bx
               : (k4 == 1) ? (31 - bx)
               : (k4 == 2) ? (bx ^ 16)
                           : (31 - (bx ^ 16));
  const int b_ = by >> 4, h_ = by & 15;
  const int qb = qt * 64;
  const int tid = threadIdx.x;
  const int lane = tid & 63, w = tid >> 6;
  const int g = lane >> 4, lr = lane & 15;
  const int qrow = qb + w * 16 + lr;

  bf16x8 qf[2];
  {
    const bf16* qp = q + (size_t)(b_ * 2048 + qrow) * 1024 + h_ * 64 + g * 8;
    qf[0] = *(const bf16x8*)qp;
    qf[1] = *(const bf16x8*)(qp + 32);
  }

  f32x4 o[4] = {};
  float l = 0.f;

  const int srow = tid >> 2;
  const int c16 = (tid & 3) * 16;
  const int rb = srow * 128;
  const int sw = (srow & 7) << 4;
  const bf16* kbase = kmat + (size_t)(b_ * 2048) * 1024 + h_ * 64;
  const bf16* vbase = vt + (size_t)(b_ * 16 + h_) * 64 * 2048;
  const bf16* kp0 = kbase + (size_t)srow * 1024 + c16;
  const bf16* vp0 = vbase + (size_t)srow * 2048 + c16;

  bf16x8 k0 = *(const bf16x8*)kp0;
  bf16x8 k1 = *(const bf16x8*)(kp0 + 8);
  bf16x8 v0 = *(const bf16x8*)vp0;
  bf16x8 v1 = *(const bf16x8*)(vp0 + 8);

  for (int s0 = 0; s0 <= qb; s0 += 64) {
    *(bf16x8*)((char*)Ks + ((rb + c16 * 2) ^ sw)) = k0;
    *(bf16x8*)((char*)Ks + ((rb + c16 * 2 + 16) ^ sw)) = k1;
    *(bf16x8*)((char*)Vs + ((rb + c16 * 2) ^ sw)) = v0;
    *(bf16x8*)((char*)Vs + ((rb + c16 * 2 + 16) ^ sw)) = v1;
    __syncthreads();
    if (s0 < qb) {  // reg-prefetch next K/V tile
      const bf16* kp = kp0 + (size_t)(s0 + 64) * 1024;
      k0 = *(const bf16x8*)kp;
      k1 = *(const bf16x8*)(kp + 8);
      const bf16* vp = vp0 + (s0 + 64);
      v0 = *(const bf16x8*)vp;
      v1 = *(const bf16x8*)(vp + 8);
    }

    f32x4 st[4];
    __builtin_amdgcn_s_setprio(1);
#pragma unroll
    for (int n = 0; n < 4; ++n) {
      f32x4 z = {};
#pragma unroll
      for (int kk = 0; kk < 2; ++kk) {
        const int row = n * 16 + lr;
        bf16x8 ak = *(const bf16x8*)((char*)Ks +
            ((row * 128 + kk * 64 + g * 16) ^ ((lr & 7) << 4)));
        z = MFMA16(ak, qf[kk], z);
      }
      st[n] = z;
    }
    __builtin_amdgcn_s_setprio(0);

    if (s0 == qb) {  // causal mask on the diagonal tile
#pragma unroll
      for (int n = 0; n < 4; ++n)
#pragma unroll
        for (int r = 0; r < 4; ++r)
          if (s0 + n * 16 + g * 4 + r > qrow) st[n][r] = -1e30f;
    }

    float rs = 0.f;
#pragma unroll
    for (int n = 0; n < 4; ++n) {
      bf16x4 pk;
#pragma unroll
      for (int r = 0; r < 4; ++r) {
        const float p = fexp2(st[n][r]);
        rs += p;
        pk[r] = (bf16)p;
      }
      *(bf16x4*)&Pq[w][lr][n * 16 + g * 4] = pk;
    }

    bf16x8 pa[2];
#pragma unroll
    for (int kk = 0; kk < 2; ++kk)
      pa[kk] = *(const bf16x8*)&Pq[w][lr][kk * 32 + g * 8];
    __builtin_amdgcn_s_setprio(1);
#pragma unroll
    for (int n = 0; n < 4; ++n) {
      const int row = n * 16 + lr;
#pragma unroll
      for (int kk = 0; kk < 2; ++kk) {
        bf16x8 bv = *(const bf16x8*)((char*)Vs +
            ((row * 128 + kk * 64 + g * 16) ^ ((lr & 7) << 4)));
        o[n] = MFMA16(pa[kk], bv, o[n]);
      }
    }
    __builtin_amdgcn_s_setprio(0);

    rs += __shfl_xor(rs, 16);
    rs += __shfl_xor(rs, 32);
    l += rs;
    __syncthreads();
  }

  float lq[4];
#pragma unroll
  for (int r = 0; r < 4; ++r) lq[r] = __shfl(l, g * 4 + r);
#pragma unroll
  for (int r = 0; r < 4; ++r) {
    const float inv = 1.0f / lq[r];
#pragma unroll
    for (int n = 0; n < 4; ++n)
      ctx[(size_t)(b_ * 2048 + qb + w * 16 + g * 4 + r) * 1024 + h_ * 64 + n * 16 + lr] =
          (bf16)(o[n][r] * inv);
  }
}

// ---------------------------------------------------------------------------
extern "C" void kernel_launch(void* const* d_in, const int* in_sizes, int n_in,
                              void* d_out, int out_size, void* d_ws, size_t ws_size,
                              hipStream_t stream)
{
  (void)in_sizes; (void)n_in; (void)out_size; (void)ws_size;
  const float* x   = (const float*)d_in[0];
  const float* Wq  = (const float*)d_in[1];
  const float* bq  = (const float*)d_in[2];
  const float* Wk  = (const float*)d_in[3];
  const float* bk  = (const float*)d_in[4];
  const float* Wv  = (const float*)d_in[5];
  const float* bv  = (const float*)d_in[6];
  const float* Wo  = (const float*)d_in[7];
  const float* bo  = (const float*)d_in[8];
  const float* W1  = (const float*)d_in[9];
  const float* b1  = (const float*)d_in[10];
  const float* W2  = (const float*)d_in[11];
  const float* b2  = (const float*)d_in[12];
  const float* g1  = (const float*)d_in[13];
  const float* be1 = (const float*)d_in[14];
  const float* g2  = (const float*)d_in[15];
  const float* be2 = (const float*)d_in[16];
  float* out = (float*)d_out;

  char* ws = (char*)d_ws;
  const size_t MB = 1024 * 1024;
  bf16* wqkv_t = (bf16*)(ws + 0 * MB);  // [3072][1024]: wq|wk|wv contiguous
  bf16* wo_t = (bf16*)(ws + 6 * MB);
  bf16* w1_t = (bf16*)(ws + 8 * MB);   // [4096][1024]
  bf16* w2_t = (bf16*)(ws + 16 * MB);  // [1024][4096]
  bf16* h1   = (bf16*)(ws + 24 * MB);  // [4096][1024]
  bf16* qbuf = (bf16*)(ws + 32 * MB);  // [4096][1024]
  bf16* kbuf = (bf16*)(ws + 40 * MB);  // [4096][1024]
  bf16* vtb  = (bf16*)(ws + 48 * MB);  // [2][16][64][2048]
  bf16* ctx  = (bf16*)(ws + 56 * MB);  // [4096][1024]
  bf16* h2   = (bf16*)(ws + 64 * MB);  // [4096][1024]
  bf16* x2b  = (bf16*)(ws + 72 * MB);  // [4096][1024] bf16 x2
  bf16* ff1  = (bf16*)(ws + 24 * MB);  // [4096][4096], overlays h1/q/k/vtb (dead)

  // all weight transposes in one launch (12288 tiles)
  transpose_all_kernel<<<12288, dim3(32, 8), 0, stream>>>(
      Wq, Wk, Wv, Wo, wqkv_t, W1, w1_t, W2, w2_t);

  ln_kernel<<<4096, 256, 0, stream>>>(x, g1, be1, h1);

  // fused QKV: -> q(prescaled), k, v(transposed)  [128x128, BK=32, XCD swz]
  gemm_bt<128, 128, 32, 4, 1><<<dim3(24, 32), 256, 0, stream>>>(
      h1, wqkv_t, bq, bk, bv, nullptr, nullptr, qbuf, kbuf, vtb, nullptr,
      4096, 3072, 1024);

  // CU-balanced attention (r14-proven): grid (32,32), 66 s-tiles per CU
  attn_kernel<<<dim3(32, 32), 256, 0, stream>>>(qbuf, kbuf, vtb, ctx);

  // x2 = x + ctx@Wo + bo -> bf16 x2b   [128x64, BK=64, 2/CU, EPI 5]
  gemm_bt<128, 64, 64, 5, 0><<<dim3(16, 32), 256, 0, stream>>>(
      ctx, wo_t, bo, nullptr, nullptr, x, nullptr, x2b, nullptr, nullptr,
      nullptr, 4096, 1024, 1024);

  ln_b_kernel<<<4096, 256, 0, stream>>>(x2b, g2, be2, h2);

  // ff1 = relu(h2 @ W1 + b1)  [256x128, BK=32, 2/CU, XCD swz]
  gemm_bt<256, 128, 32, 1, 1><<<dim3(32, 16), 256, 0, stream>>>(
      h2, w1_t, b1, nullptr, nullptr, nullptr, nullptr, ff1, nullptr, nullptr,
      nullptr, 4096, 4096, 1024);

  // out = x2b + ff1@W2 + b2 -> d_out (f32)  [128x64, BK=64, XCD swz, EPI 6]
  gemm_bt<128, 64, 64, 6, 1><<<dim3(16, 32), 256, 0, stream>>>(
      ff1, w2_t, b2, nullptr, nullptr, nullptr, x2b, nullptr, nullptr, nullptr,
      out, 4096, 1024, 4096);
}

// Round 18
// 196.373 us; speedup vs baseline: 1.4102x; 1.0019x over previous
//
#include <hip/hip_runtime.h>

typedef __bf16 bf16;
typedef __attribute__((ext_vector_type(8))) __bf16 bf16x8;
typedef __attribute__((ext_vector_type(4))) __bf16 bf16x4;
typedef __attribute__((ext_vector_type(4))) float f32x4;

#define MFMA16(A, B, C) __builtin_amdgcn_mfma_f32_16x16x32_bf16(A, B, C, 0, 0, 0)

// async global->LDS, 16B per lane: dest = (wave-uniform base) + lane*16
#define GLOAD16(gp, lp)                                          \
  __builtin_amdgcn_global_load_lds(                              \
      (const __attribute__((address_space(1))) void*)(gp),       \
      (__attribute__((address_space(3))) void*)(lp), 16, 0, 0)

// 2^x (v_exp_f32 computes 2^S0)
__device__ __forceinline__ float fexp2(float x) {
#if __has_builtin(__builtin_amdgcn_exp2f)
  return __builtin_amdgcn_exp2f(x);
#else
  float r;
  asm("v_exp_f32 %0, %1" : "=v"(r) : "v"(x));
  return r;
#endif
}

// Q pre-scale: scores = (q.k)/sqrt(64) in log2 units for exp2-softmax
#define QSCL 0.18033688011112042f  // 0.125 * log2(e)

// ---------------------------------------------------------------------------
// All weight transposes in ONE launch (fp32 -> bf16)
// ---------------------------------------------------------------------------
__global__ __launch_bounds__(256) void transpose_all_kernel(
    const float* __restrict__ w0, const float* __restrict__ w1,
    const float* __restrict__ w2, const float* __restrict__ w3,
    bf16* __restrict__ out4,
    const float* __restrict__ W1, bf16* __restrict__ w1t,
    const float* __restrict__ W2, bf16* __restrict__ w2t)
{
  __shared__ float tile[32][33];
  const int bid = blockIdx.x;
  const float* in;
  bf16* out;
  int K, N, kt, nt;
  if (bid < 4096) {
    const float* srcs[4] = {w0, w1, w2, w3};
    in = srcs[bid >> 10];
    out = out4 + (size_t)(bid >> 10) * 1024 * 1024;
    K = 1024; N = 1024;
    const int t = bid & 1023;
    nt = (t & 31) * 32; kt = (t >> 5) * 32;
  } else if (bid < 8192) {
    in = W1; out = w1t; K = 1024; N = 4096;
    const int t = bid - 4096;
    nt = (t & 127) * 32; kt = (t >> 7) * 32;
  } else {
    in = W2; out = w2t; K = 4096; N = 1024;
    const int t = bid - 8192;
    nt = (t & 31) * 32; kt = (t >> 5) * 32;
  }
  const int tx = threadIdx.x, ty = threadIdx.y;
#pragma unroll
  for (int j = 0; j < 4; ++j)
    tile[ty + j * 8][tx] = in[(size_t)(kt + ty + j * 8) * N + nt + tx];
  __syncthreads();
#pragma unroll
  for (int j = 0; j < 4; ++j)
    out[(size_t)(nt + ty + j * 8) * K + kt + tx] = (bf16)tile[tx][ty + j * 8];
}

// ---------------------------------------------------------------------------
// LayerNorm (eps=1e-3), fp32 in -> bf16 out. One block per row of 1024.
// ---------------------------------------------------------------------------
__global__ __launch_bounds__(256) void ln_kernel(
    const float* __restrict__ in, const float* __restrict__ gamma,
    const float* __restrict__ beta, bf16* __restrict__ out)
{
  const int row = blockIdx.x;
  const int t = threadIdx.x;
  const float4 v = ((const float4*)(in + (size_t)row * 1024))[t];
  float s = v.x + v.y + v.z + v.w;
  float sq = v.x * v.x + v.y * v.y + v.z * v.z + v.w * v.w;
#pragma unroll
  for (int m = 1; m < 64; m <<= 1) {
    s += __shfl_xor(s, m);
    sq += __shfl_xor(sq, m);
  }
  __shared__ float ssum[4], ssq[4];
  const int w = t >> 6;
  if ((t & 63) == 0) { ssum[w] = s; ssq[w] = sq; }
  __syncthreads();
  s = ssum[0] + ssum[1] + ssum[2] + ssum[3];
  sq = ssq[0] + ssq[1] + ssq[2] + ssq[3];
  const float mu = s * (1.0f / 1024.0f);
  const float var = sq * (1.0f / 1024.0f) - mu * mu;
  const float rs = rsqrtf(var + 1e-3f);
  const float4 g = ((const float4*)gamma)[t];
  const float4 b = ((const float4*)beta)[t];
  bf16x4 o;
  o[0] = (bf16)((v.x - mu) * rs * g.x + b.x);
  o[1] = (bf16)((v.y - mu) * rs * g.y + b.y);
  o[2] = (bf16)((v.z - mu) * rs * g.z + b.z);
  o[3] = (bf16)((v.w - mu) * rs * g.w + b.w);
  *(bf16x4*)(out + (size_t)row * 1024 + t * 4) = o;
}

// LayerNorm, bf16 in -> bf16 out (for the bf16 x2 chain)
__global__ __launch_bounds__(256) void ln_b_kernel(
    const bf16* __restrict__ in, const float* __restrict__ gamma,
    const float* __restrict__ beta, bf16* __restrict__ out)
{
  const int row = blockIdx.x;
  const int t = threadIdx.x;
  const bf16x4 vb = *(const bf16x4*)(in + (size_t)row * 1024 + t * 4);
  float v0 = (float)vb[0], v1 = (float)vb[1], v2 = (float)vb[2], v3 = (float)vb[3];
  float s = v0 + v1 + v2 + v3;
  float sq = v0 * v0 + v1 * v1 + v2 * v2 + v3 * v3;
#pragma unroll
  for (int m = 1; m < 64; m <<= 1) {
    s += __shfl_xor(s, m);
    sq += __shfl_xor(sq, m);
  }
  __shared__ float ssum[4], ssq[4];
  const int w = t >> 6;
  if ((t & 63) == 0) { ssum[w] = s; ssq[w] = sq; }
  __syncthreads();
  s = ssum[0] + ssum[1] + ssum[2] + ssum[3];
  sq = ssq[0] + ssq[1] + ssq[2] + ssq[3];
  const float mu = s * (1.0f / 1024.0f);
  const float var = sq * (1.0f / 1024.0f) - mu * mu;
  const float rs = rsqrtf(var + 1e-3f);
  const float4 g = ((const float4*)gamma)[t];
  const float4 b = ((const float4*)beta)[t];
  bf16x4 o;
  o[0] = (bf16)((v0 - mu) * rs * g.x + b.x);
  o[1] = (bf16)((v1 - mu) * rs * g.y + b.y);
  o[2] = (bf16)((v2 - mu) * rs * g.z + b.z);
  o[3] = (bf16)((v3 - mu) * rs * g.w + b.w);
  *(bf16x4*)(out + (size_t)row * 1024 + t * 4) = o;
}

// ---------------------------------------------------------------------------
// GEMM: C[M,N] = epilogue(A[M,K] @ Bt[N,K]^T + bias)
// 3 LDS buffers, prefetch distance 2 via global_load_lds, counted vmcnt,
// raw s_barrier, T5 setprio, both-sides swizzle (XOR @BK64, ROT @BK32).
// SWZ=1: XCD by-chunk grid remap (localize A panels per XCD L2).
// EPI 1: bf16 relu            EPI 4: fused QKV epilogue
// EPI 5: bf16 out = acc+bias+resid(f32)     (O-proj -> x2 bf16)
// EPI 6: f32 out = acc+bias+residb(bf16)    (FF2 -> d_out)
// ---------------------------------------------------------------------------
template <int BM, int BN, int BK, int EPI, int SWZ>
__global__ __launch_bounds__(256, 2) void gemm_bt(
    const bf16* __restrict__ A, const bf16* __restrict__ Bt,
    const float* __restrict__ bias0, const float* __restrict__ bias1,
    const float* __restrict__ bias2, const float* __restrict__ resid,
    const bf16* __restrict__ residb,
    bf16* __restrict__ out0, bf16* __restrict__ out1, bf16* __restrict__ out2,
    float* __restrict__ outf, int M, int N, int K)
{
  constexpr int WM = BM / 2, WN = BN / 2;
  constexpr int MI = WM / 16, NJ = WN / 16;
  constexpr int KK = BK / 32;
  constexpr int NSLOT = BK / 8;
  constexpr int SMASK = NSLOT - 1;
  constexpr int RPL = 512 / BK;             // rows per gload16
  constexpr int ALOADS = BM / (4 * RPL);
  constexpr int BLOADS = BN / (4 * RPL);
  constexpr int S = ALOADS + BLOADS;

  __shared__ bf16 As[3][BM * BK];
  __shared__ bf16 Bs[3][BN * BK];
  const int tid = threadIdx.x;
  const int lane = tid & 63, w = tid >> 6;
  const int wr = w >> 1, wc = w & 1;
  const int g = lane >> 4, lr = lane & 15;

  int bx = blockIdx.x, by = blockIdx.y;
  if constexpr (SWZ) {  // XCD by-chunking: each XCD owns a contiguous by range
    const int bid = bx + gridDim.x * by;
    const int xcd = bid & 7, idx = bid >> 3;
    const int chunk = gridDim.y >> 3;
    by = xcd * chunk + (idx % chunk);
    bx = idx / chunk;
  }
  const int brow = by * BM, bcol = bx * BN;

  f32x4 acc[MI][NJ] = {};

  const int lrow = lane / NSLOT;            // row within a gload group
  const int slot = lane & SMASK;            // linear LDS 16B slot
  int lcol;
  if constexpr (BK == 32)
    lcol = ((slot - (lrow >> 1)) & 3) * 8;  // rotation involution
  else
    lcol = (slot ^ (lrow & 7)) * 8;         // XOR

  auto stage = [&](int buf, int k0) {
#pragma unroll
    for (int j = 0; j < ALOADS; ++j) {
      const int row0 = w * (BM / 4) + j * RPL;
      GLOAD16(A + (size_t)(brow + row0 + lrow) * K + k0 + lcol,
              &As[buf][row0 * BK]);
    }
#pragma unroll
    for (int j = 0; j < BLOADS; ++j) {
      const int row0 = w * (BN / 4) + j * RPL;
      GLOAD16(Bt + (size_t)(bcol + row0 + lrow) * K + k0 + lcol,
              &Bs[buf][row0 * BK]);
    }
  };

  auto rdslot = [&](int kg) {  // swizzled 16B-slot index for k-group kg
    if constexpr (BK == 32) return ((kg + (lr >> 1)) & 3) * 8;
    else return (kg ^ (lr & 7)) * 8;
  };

  const int nk = K / BK;
  stage(0, 0);
  stage(1, BK);
  int cur = 0;
  for (int t = 0; t < nk; ++t) {
    if (t + 1 < nk) {
      if constexpr (S == 3)
        asm volatile("s_waitcnt vmcnt(3)" ::: "memory");
      else if constexpr (S == 4)
        asm volatile("s_waitcnt vmcnt(4)" ::: "memory");
      else
        asm volatile("s_waitcnt vmcnt(6)" ::: "memory");
    } else {
      asm volatile("s_waitcnt vmcnt(0)" ::: "memory");
    }
    __builtin_amdgcn_s_barrier();
    __builtin_amdgcn_sched_barrier(0);

    bf16x8 afr[MI][KK], bfr[NJ][KK];
#pragma unroll
    for (int i = 0; i < MI; ++i)
#pragma unroll
      for (int kk = 0; kk < KK; ++kk)
        afr[i][kk] = *(const bf16x8*)&As[cur][(wr * WM + i * 16 + lr) * BK +
                                             rdslot(kk * 4 + g)];
#pragma unroll
    for (int j = 0; j < NJ; ++j)
#pragma unroll
      for (int kk = 0; kk < KK; ++kk)
        bfr[j][kk] = *(const bf16x8*)&Bs[cur][(wc * WN + j * 16 + lr) * BK +
                                             rdslot(kk * 4 + g)];

    if (t + 2 < nk) {
      int nb = cur + 2;
      if (nb >= 3) nb -= 3;
      stage(nb, (t + 2) * BK);
    }

    __builtin_amdgcn_s_setprio(1);
#pragma unroll
    for (int kk = 0; kk < KK; ++kk)
#pragma unroll
      for (int i = 0; i < MI; ++i)
#pragma unroll
        for (int j = 0; j < NJ; ++j)
          acc[i][j] = MFMA16(afr[i][kk], bfr[j][kk], acc[i][j]);
    __builtin_amdgcn_s_setprio(0);

    ++cur;
    if (cur == 3) cur = 0;
  }

#pragma unroll
  for (int i = 0; i < MI; ++i) {
#pragma unroll
    for (int j = 0; j < NJ; ++j) {
      const int r0 = brow + wr * WM + i * 16 + g * 4;
      const int c = bcol + wc * WN + j * 16 + lr;
      if constexpr (EPI == 1) {
        const float bv = bias0[c];
#pragma unroll
        for (int rr = 0; rr < 4; ++rr)
          out0[(size_t)(r0 + rr) * N + c] =
              (bf16)fmaxf(acc[i][j][rr] + bv, 0.0f);
      } else if constexpr (EPI == 5) {
        const float bv = bias0[c];
#pragma unroll
        for (int rr = 0; rr < 4; ++rr) {
          const size_t idx = (size_t)(r0 + rr) * N + c;
          out0[idx] = (bf16)(acc[i][j][rr] + bv + resid[idx]);
        }
      } else if constexpr (EPI == 6) {
        const float bv = bias0[c];
#pragma unroll
        for (int rr = 0; rr < 4; ++rr) {
          const size_t idx = (size_t)(r0 + rr) * N + c;
          outf[idx] = acc[i][j][rr] + bv + (float)residb[idx];
        }
      } else {  // EPI 4: fused QKV
        const int sub = c >> 10;
        const int c1 = c & 1023;
        if (sub == 0) {  // Q, pre-scaled into log2-softmax units
          const float bv = bias0[c1];
#pragma unroll
          for (int rr = 0; rr < 4; ++rr)
            out0[(size_t)(r0 + rr) * 1024 + c1] =
                (bf16)((acc[i][j][rr] + bv) * QSCL);
        } else if (sub == 1) {
          const float bv = bias1[c1];
#pragma unroll
          for (int rr = 0; rr < 4; ++rr)
            out1[(size_t)(r0 + rr) * 1024 + c1] = (bf16)(acc[i][j][rr] + bv);
        } else {
          const float bv = bias2[c1];
          const int bb = r0 >> 11, t0 = r0 & 2047;
          const int hh = c1 >> 6, dd = c1 & 63;
          bf16x4 pk;
#pragma unroll
          for (int rr = 0; rr < 4; ++rr) pk[rr] = (bf16)(acc[i][j][rr] + bv);
          *(bf16x4*)(out2 + ((size_t)((bb * 16 + hh) * 64 + dd)) * 2048 + t0) = pk;
        }
      }
    }
  }
}

// ---------------------------------------------------------------------------
// Causal flash attention, S^T formulation, exp2-softmax (no max-tracking).
// r12/r14-proven body: k4-balanced qt map, 64-s tiles, XOR-swizzled K/V LDS,
// reg-prefetch across barrier, T5 setprio, overlapped l-reduce.
// This structure's empirical plateau ~44 us (6 structural variants tested).
// ---------------------------------------------------------------------------
__global__ __launch_bounds__(256) void attn_kernel(
    const bf16* __restrict__ q, const bf16* __restrict__ kmat,
    const bf16* __restrict__ vt, bf16* __restrict__ ctx)
{
  __shared__ bf16 Ks[64 * 64];
  __shared__ bf16 Vs[64 * 64];
  __shared__ bf16 Pq[4][16][88];
  const int bx = blockIdx.x, by = blockIdx.y;
  const int k4 = by >> 3;
  const int qt = (k4 == 0) ? bx
               : (k4 == 1) ? (31 - bx)
               : (k4 == 2) ? (bx ^ 16)
                           : (31 - (bx ^ 16));
  const int b_ = by >> 4, h_ = by & 15;
  const int qb = qt * 64;
  const int tid = threadIdx.x;
  const int lane = tid & 63, w = tid >> 6;
  const int g = lane >> 4, lr = lane & 15;
  const int qrow = qb + w * 16 + lr;

  bf16x8 qf[2];
  {
    const bf16* qp = q + (size_t)(b_ * 2048 + qrow) * 1024 + h_ * 64 + g * 8;
    qf[0] = *(const bf16x8*)qp;
    qf[1] = *(const bf16x8*)(qp + 32);
  }

  f32x4 o[4] = {};
  float l = 0.f;

  const int srow = tid >> 2;
  const int c16 = (tid & 3) * 16;
  const int rb = srow * 128;
  const int sw = (srow & 7) << 4;
  const bf16* kbase = kmat + (size_t)(b_ * 2048) * 1024 + h_ * 64;
  const bf16* vbase = vt + (size_t)(b_ * 16 + h_) * 64 * 2048;
  const bf16* kp0 = kbase + (size_t)srow * 1024 + c16;
  const bf16* vp0 = vbase + (size_t)srow * 2048 + c16;

  bf16x8 k0 = *(const bf16x8*)kp0;
  bf16x8 k1 = *(const bf16x8*)(kp0 + 8);
  bf16x8 v0 = *(const bf16x8*)vp0;
  bf16x8 v1 = *(const bf16x8*)(vp0 + 8);

  for (int s0 = 0; s0 <= qb; s0 += 64) {
    *(bf16x8*)((char*)Ks + ((rb + c16 * 2) ^ sw)) = k0;
    *(bf16x8*)((char*)Ks + ((rb + c16 * 2 + 16) ^ sw)) = k1;
    *(bf16x8*)((char*)Vs + ((rb + c16 * 2) ^ sw)) = v0;
    *(bf16x8*)((char*)Vs + ((rb + c16 * 2 + 16) ^ sw)) = v1;
    __syncthreads();
    if (s0 < qb) {  // reg-prefetch next K/V tile
      const bf16* kp = kp0 + (size_t)(s0 + 64) * 1024;
      k0 = *(const bf16x8*)kp;
      k1 = *(const bf16x8*)(kp + 8);
      const bf16* vp = vp0 + (s0 + 64);
      v0 = *(const bf16x8*)vp;
      v1 = *(const bf16x8*)(vp + 8);
    }

    f32x4 st[4];
    __builtin_amdgcn_s_setprio(1);
#pragma unroll
    for (int n = 0; n < 4; ++n) {
      f32x4 z = {};
#pragma unroll
      for (int kk = 0; kk < 2; ++kk) {
        const int row = n * 16 + lr;
        bf16x8 ak = *(const bf16x8*)((char*)Ks +
            ((row * 128 + kk * 64 + g * 16) ^ ((lr & 7) << 4)));
        z = MFMA16(ak, qf[kk], z);
      }
      st[n] = z;
    }
    __builtin_amdgcn_s_setprio(0);

    if (s0 == qb) {  // causal mask on the diagonal tile
#pragma unroll
      for (int n = 0; n < 4; ++n)
#pragma unroll
        for (int r = 0; r < 4; ++r)
          if (s0 + n * 16 + g * 4 + r > qrow) st[n][r] = -1e30f;
    }

    float rs = 0.f;
#pragma unroll
    for (int n = 0; n < 4; ++n) {
      bf16x4 pk;
#pragma unroll
      for (int r = 0; r < 4; ++r) {
        const float p = fexp2(st[n][r]);
        rs += p;
        pk[r] = (bf16)p;
      }
      *(bf16x4*)&Pq[w][lr][n * 16 + g * 4] = pk;
    }

    bf16x8 pa[2];
#pragma unroll
    for (int kk = 0; kk < 2; ++kk)
      pa[kk] = *(const bf16x8*)&Pq[w][lr][kk * 32 + g * 8];
    __builtin_amdgcn_s_setprio(1);
#pragma unroll
    for (int n = 0; n < 4; ++n) {
      const int row = n * 16 + lr;
#pragma unroll
      for (int kk = 0; kk < 2; ++kk) {
        bf16x8 bv = *(const bf16x8*)((char*)Vs +
            ((row * 128 + kk * 64 + g * 16) ^ ((lr & 7) << 4)));
        o[n] = MFMA16(pa[kk], bv, o[n]);
      }
    }
    __builtin_amdgcn_s_setprio(0);

    rs += __shfl_xor(rs, 16);
    rs += __shfl_xor(rs, 32);
    l += rs;
    __syncthreads();
  }

  float lq[4];
#pragma unroll
  for (int r = 0; r < 4; ++r) lq[r] = __shfl(l, g * 4 + r);
#pragma unroll
  for (int r = 0; r < 4; ++r) {
    const float inv = 1.0f / lq[r];
#pragma unroll
    for (int n = 0; n < 4; ++n)
      ctx[(size_t)(b_ * 2048 + qb + w * 16 + g * 4 + r) * 1024 + h_ * 64 + n * 16 + lr] =
          (bf16)(o[n][r] * inv);
  }
}

// ---------------------------------------------------------------------------
extern "C" void kernel_launch(void* const* d_in, const int* in_sizes, int n_in,
                              void* d_out, int out_size, void* d_ws, size_t ws_size,
                              hipStream_t stream)
{
  (void)in_sizes; (void)n_in; (void)out_size; (void)ws_size;
  const float* x   = (const float*)d_in[0];
  const float* Wq  = (const float*)d_in[1];
  const float* bq  = (const float*)d_in[2];
  const float* Wk  = (const float*)d_in[3];
  const float* bk  = (const float*)d_in[4];
  const float* Wv  = (const float*)d_in[5];
  const float* bv  = (const float*)d_in[6];
  const float* Wo  = (const float*)d_in[7];
  const float* bo  = (const float*)d_in[8];
  const float* W1  = (const float*)d_in[9];
  const float* b1  = (const float*)d_in[10];
  const float* W2  = (const float*)d_in[11];
  const float* b2  = (const float*)d_in[12];
  const float* g1  = (const float*)d_in[13];
  const float* be1 = (const float*)d_in[14];
  const float* g2  = (const float*)d_in[15];
  const float* be2 = (const float*)d_in[16];
  float* out = (float*)d_out;

  char* ws = (char*)d_ws;
  const size_t MB = 1024 * 1024;
  bf16* wqkv_t = (bf16*)(ws + 0 * MB);  // [3072][1024]: wq|wk|wv contiguous
  bf16* wo_t = (bf16*)(ws + 6 * MB);
  bf16* w1_t = (bf16*)(ws + 8 * MB);   // [4096][1024]
  bf16* w2_t = (bf16*)(ws + 16 * MB);  // [1024][4096]
  bf16* h1   = (bf16*)(ws + 24 * MB);  // [4096][1024]
  bf16* qbuf = (bf16*)(ws + 32 * MB);  // [4096][1024]
  bf16* kbuf = (bf16*)(ws + 40 * MB);  // [4096][1024]
  bf16* vtb  = (bf16*)(ws + 48 * MB);  // [2][16][64][2048]
  bf16* ctx  = (bf16*)(ws + 56 * MB);  // [4096][1024]
  bf16* h2   = (bf16*)(ws + 64 * MB);  // [4096][1024]
  bf16* x2b  = (bf16*)(ws + 72 * MB);  // [4096][1024] bf16 x2
  bf16* ff1  = (bf16*)(ws + 24 * MB);  // [4096][4096], overlays h1/q/k/vtb (dead)

  // all weight transposes in one launch (12288 tiles)
  transpose_all_kernel<<<12288, dim3(32, 8), 0, stream>>>(
      Wq, Wk, Wv, Wo, wqkv_t, W1, w1_t, W2, w2_t);

  ln_kernel<<<4096, 256, 0, stream>>>(x, g1, be1, h1);

  // fused QKV: -> q(prescaled), k, v(transposed)  [128x128, BK=32, XCD swz]
  gemm_bt<128, 128, 32, 4, 1><<<dim3(24, 32), 256, 0, stream>>>(
      h1, wqkv_t, bq, bk, bv, nullptr, nullptr, qbuf, kbuf, vtb, nullptr,
      4096, 3072, 1024);

  // CU-balanced attention (r14-proven): grid (32,32), 66 s-tiles per CU
  attn_kernel<<<dim3(32, 32), 256, 0, stream>>>(qbuf, kbuf, vtb, ctx);

  // x2 = x + ctx@Wo + bo -> bf16 x2b   [128x64, BK=64, 2/CU, EPI 5]
  gemm_bt<128, 64, 64, 5, 0><<<dim3(16, 32), 256, 0, stream>>>(
      ctx, wo_t, bo, nullptr, nullptr, x, nullptr, x2b, nullptr, nullptr,
      nullptr, 4096, 1024, 1024);

  ln_b_kernel<<<4096, 256, 0, stream>>>(x2b, g2, be2, h2);

  // ff1 = relu(h2 @ W1 + b1)  [256x128, BK=32, 2/CU, XCD swz]
  gemm_bt<256, 128, 32, 1, 1><<<dim3(32, 16), 256, 0, stream>>>(
      h2, w1_t, b1, nullptr, nullptr, nullptr, nullptr, ff1, nullptr, nullptr,
      nullptr, 4096, 4096, 1024);

  // out = x2b + ff1@W2 + b2 -> d_out (f32)  [128x64, BK=64, XCD swz, EPI 6]
  gemm_bt<128, 64, 64, 6, 1><<<dim3(16, 32), 256, 0, stream>>>(
      ff1, w2_t, b2, nullptr, nullptr, nullptr, x2b, nullptr, nullptr, nullptr,
      out, 4096, 1024, 4096);
}

// Round 19
// 195.134 us; speedup vs baseline: 1.4192x; 1.0063x over previous
//
#include <hip/hip_runtime.h>

typedef __bf16 bf16;
typedef __attribute__((ext_vector_type(8))) __bf16 bf16x8;
typedef __attribute__((ext_vector_type(4))) __bf16 bf16x4;
typedef __attribute__((ext_vector_type(4))) float f32x4;

#define MFMA16(A, B, C) __builtin_amdgcn_mfma_f32_16x16x32_bf16(A, B, C, 0, 0, 0)

// async global->LDS, 16B per lane: dest = (wave-uniform base) + lane*16
#define GLOAD16(gp, lp)                                          \
  __builtin_amdgcn_global_load_lds(                              \
      (const __attribute__((address_space(1))) void*)(gp),       \
      (__attribute__((address_space(3))) void*)(lp), 16, 0, 0)

// 2^x (v_exp_f32 computes 2^S0)
__device__ __forceinline__ float fexp2(float x) {
#if __has_builtin(__builtin_amdgcn_exp2f)
  return __builtin_amdgcn_exp2f(x);
#else
  float r;
  asm("v_exp_f32 %0, %1" : "=v"(r) : "v"(x));
  return r;
#endif
}

// Q pre-scale: scores = (q.k)/sqrt(64) in log2 units for exp2-softmax
#define QSCL 0.18033688011112042f  // 0.125 * log2(e)

// ---------------------------------------------------------------------------
// Prologue mega-kernel: all weight transposes (fp32->bf16) + LayerNorm1.
//  bid <  4096 : Wq/Wk/Wv/Wo 1024x1024 (quadrant bid>>10) -> out4 strided 1M
//  bid <  8192 : W1 1024x4096 -> w1t [4096][1024]
//  bid < 12288 : W2 4096x1024 -> w2t [1024][4096]
//  else        : LN1 row (bid-12288) of x -> h1 (bf16)
// Branch is block-uniform. LN overlaps transpose BW in one launch.
// ---------------------------------------------------------------------------
__global__ __launch_bounds__(256) void prologue_kernel(
    const float* __restrict__ w0, const float* __restrict__ w1,
    const float* __restrict__ w2, const float* __restrict__ w3,
    bf16* __restrict__ out4,
    const float* __restrict__ W1, bf16* __restrict__ w1t,
    const float* __restrict__ W2, bf16* __restrict__ w2t,
    const float* __restrict__ x, const float* __restrict__ gamma,
    const float* __restrict__ beta, bf16* __restrict__ h1)
{
  __shared__ float tile[32][33];
  __shared__ float ssum[4], ssq[4];
  const int bid = blockIdx.x;

  if (bid >= 12288) {  // -------- LayerNorm1 row
    const int row = bid - 12288;
    const int t = threadIdx.y * 32 + threadIdx.x;
    const float4 v = ((const float4*)(x + (size_t)row * 1024))[t];
    float s = v.x + v.y + v.z + v.w;
    float sq = v.x * v.x + v.y * v.y + v.z * v.z + v.w * v.w;
#pragma unroll
    for (int m = 1; m < 64; m <<= 1) {
      s += __shfl_xor(s, m);
      sq += __shfl_xor(sq, m);
    }
    const int wv = t >> 6;
    if ((t & 63) == 0) { ssum[wv] = s; ssq[wv] = sq; }
    __syncthreads();
    s = ssum[0] + ssum[1] + ssum[2] + ssum[3];
    sq = ssq[0] + ssq[1] + ssq[2] + ssq[3];
    const float mu = s * (1.0f / 1024.0f);
    const float var = sq * (1.0f / 1024.0f) - mu * mu;
    const float rs = rsqrtf(var + 1e-3f);
    const float4 g = ((const float4*)gamma)[t];
    const float4 b = ((const float4*)beta)[t];
    bf16x4 o;
    o[0] = (bf16)((v.x - mu) * rs * g.x + b.x);
    o[1] = (bf16)((v.y - mu) * rs * g.y + b.y);
    o[2] = (bf16)((v.z - mu) * rs * g.z + b.z);
    o[3] = (bf16)((v.w - mu) * rs * g.w + b.w);
    *(bf16x4*)(h1 + (size_t)row * 1024 + t * 4) = o;
    return;
  }

  // -------- weight transpose tile
  const float* in;
  bf16* out;
  int K, N, kt, nt;
  if (bid < 4096) {
    const float* srcs[4] = {w0, w1, w2, w3};
    in = srcs[bid >> 10];
    out = out4 + (size_t)(bid >> 10) * 1024 * 1024;
    K = 1024; N = 1024;
    const int t = bid & 1023;
    nt = (t & 31) * 32; kt = (t >> 5) * 32;
  } else if (bid < 8192) {
    in = W1; out = w1t; K = 1024; N = 4096;
    const int t = bid - 4096;
    nt = (t & 127) * 32; kt = (t >> 7) * 32;
  } else {
    in = W2; out = w2t; K = 4096; N = 1024;
    const int t = bid - 8192;
    nt = (t & 31) * 32; kt = (t >> 5) * 32;
  }
  const int tx = threadIdx.x, ty = threadIdx.y;
#pragma unroll
  for (int j = 0; j < 4; ++j)
    tile[ty + j * 8][tx] = in[(size_t)(kt + ty + j * 8) * N + nt + tx];
  __syncthreads();
#pragma unroll
  for (int j = 0; j < 4; ++j)
    out[(size_t)(nt + ty + j * 8) * K + kt + tx] = (bf16)tile[tx][ty + j * 8];
}

// LayerNorm, bf16 in -> bf16 out (for the bf16 x2 chain)
__global__ __launch_bounds__(256) void ln_b_kernel(
    const bf16* __restrict__ in, const float* __restrict__ gamma,
    const float* __restrict__ beta, bf16* __restrict__ out)
{
  const int row = blockIdx.x;
  const int t = threadIdx.x;
  const bf16x4 vb = *(const bf16x4*)(in + (size_t)row * 1024 + t * 4);
  float v0 = (float)vb[0], v1 = (float)vb[1], v2 = (float)vb[2], v3 = (float)vb[3];
  float s = v0 + v1 + v2 + v3;
  float sq = v0 * v0 + v1 * v1 + v2 * v2 + v3 * v3;
#pragma unroll
  for (int m = 1; m < 64; m <<= 1) {
    s += __shfl_xor(s, m);
    sq += __shfl_xor(sq, m);
  }
  __shared__ float ssum[4], ssq[4];
  const int w = t >> 6;
  if ((t & 63) == 0) { ssum[w] = s; ssq[w] = sq; }
  __syncthreads();
  s = ssum[0] + ssum[1] + ssum[2] + ssum[3];
  sq = ssq[0] + ssq[1] + ssq[2] + ssq[3];
  const float mu = s * (1.0f / 1024.0f);
  const float var = sq * (1.0f / 1024.0f) - mu * mu;
  const float rs = rsqrtf(var + 1e-3f);
  const float4 g = ((const float4*)gamma)[t];
  const float4 b = ((const float4*)beta)[t];
  bf16x4 o;
  o[0] = (bf16)((v0 - mu) * rs * g.x + b.x);
  o[1] = (bf16)((v1 - mu) * rs * g.y + b.y);
  o[2] = (bf16)((v2 - mu) * rs * g.z + b.z);
  o[3] = (bf16)((v3 - mu) * rs * g.w + b.w);
  *(bf16x4*)(out + (size_t)row * 1024 + t * 4) = o;
}

// ---------------------------------------------------------------------------
// GEMM: C[M,N] = epilogue(A[M,K] @ Bt[N,K]^T + bias)
// 3 LDS buffers, prefetch distance 2 via global_load_lds, counted vmcnt,
// raw s_barrier, T5 setprio, both-sides swizzle (XOR @BK64, ROT @BK32).
// SWZ=1: XCD by-chunk grid remap (localize A panels per XCD L2).
// EPI 1: bf16 relu            EPI 4: fused QKV epilogue
// EPI 5: bf16 out = acc+bias+resid(f32)     (O-proj -> x2 bf16)
// EPI 6: f32 out = acc+bias+residb(bf16)    (FF2 -> d_out)
// ---------------------------------------------------------------------------
template <int BM, int BN, int BK, int EPI, int SWZ>
__global__ __launch_bounds__(256, 2) void gemm_bt(
    const bf16* __restrict__ A, const bf16* __restrict__ Bt,
    const float* __restrict__ bias0, const float* __restrict__ bias1,
    const float* __restrict__ bias2, const float* __restrict__ resid,
    const bf16* __restrict__ residb,
    bf16* __restrict__ out0, bf16* __restrict__ out1, bf16* __restrict__ out2,
    float* __restrict__ outf, int M, int N, int K)
{
  constexpr int WM = BM / 2, WN = BN / 2;
  constexpr int MI = WM / 16, NJ = WN / 16;
  constexpr int KK = BK / 32;
  constexpr int NSLOT = BK / 8;
  constexpr int SMASK = NSLOT - 1;
  constexpr int RPL = 512 / BK;             // rows per gload16
  constexpr int ALOADS = BM / (4 * RPL);
  constexpr int BLOADS = BN / (4 * RPL);
  constexpr int S = ALOADS + BLOADS;

  __shared__ bf16 As[3][BM * BK];
  __shared__ bf16 Bs[3][BN * BK];
  const int tid = threadIdx.x;
  const int lane = tid & 63, w = tid >> 6;
  const int wr = w >> 1, wc = w & 1;
  const int g = lane >> 4, lr = lane & 15;

  int bx = blockIdx.x, by = blockIdx.y;
  if constexpr (SWZ) {  // XCD by-chunking: each XCD owns a contiguous by range
    const int bid = bx + gridDim.x * by;
    const int xcd = bid & 7, idx = bid >> 3;
    const int chunk = gridDim.y >> 3;
    by = xcd * chunk + (idx % chunk);
    bx = idx / chunk;
  }
  const int brow = by * BM, bcol = bx * BN;

  f32x4 acc[MI][NJ] = {};

  const int lrow = lane / NSLOT;            // row within a gload group
  const int slot = lane & SMASK;            // linear LDS 16B slot
  int lcol;
  if constexpr (BK == 32)
    lcol = ((slot - (lrow >> 1)) & 3) * 8;  // rotation involution
  else
    lcol = (slot ^ (lrow & 7)) * 8;         // XOR

  auto stage = [&](int buf, int k0) {
#pragma unroll
    for (int j = 0; j < ALOADS; ++j) {
      const int row0 = w * (BM / 4) + j * RPL;
      GLOAD16(A + (size_t)(brow + row0 + lrow) * K + k0 + lcol,
              &As[buf][row0 * BK]);
    }
#pragma unroll
    for (int j = 0; j < BLOADS; ++j) {
      const int row0 = w * (BN / 4) + j * RPL;
      GLOAD16(Bt + (size_t)(bcol + row0 + lrow) * K + k0 + lcol,
              &Bs[buf][row0 * BK]);
    }
  };

  auto rdslot = [&](int kg) {  // swizzled 16B-slot index for k-group kg
    if constexpr (BK == 32) return ((kg + (lr >> 1)) & 3) * 8;
    else return (kg ^ (lr & 7)) * 8;
  };

  const int nk = K / BK;
  stage(0, 0);
  stage(1, BK);
  int cur = 0;
  for (int t = 0; t < nk; ++t) {
    if (t + 1 < nk) {
      if constexpr (S == 3)
        asm volatile("s_waitcnt vmcnt(3)" ::: "memory");
      else if constexpr (S == 4)
        asm volatile("s_waitcnt vmcnt(4)" ::: "memory");
      else
        asm volatile("s_waitcnt vmcnt(6)" ::: "memory");
    } else {
      asm volatile("s_waitcnt vmcnt(0)" ::: "memory");
    }
    __builtin_amdgcn_s_barrier();
    __builtin_amdgcn_sched_barrier(0);

    bf16x8 afr[MI][KK], bfr[NJ][KK];
#pragma unroll
    for (int i = 0; i < MI; ++i)
#pragma unroll
      for (int kk = 0; kk < KK; ++kk)
        afr[i][kk] = *(const bf16x8*)&As[cur][(wr * WM + i * 16 + lr) * BK +
                                             rdslot(kk * 4 + g)];
#pragma unroll
    for (int j = 0; j < NJ; ++j)
#pragma unroll
      for (int kk = 0; kk < KK; ++kk)
        bfr[j][kk] = *(const bf16x8*)&Bs[cur][(wc * WN + j * 16 + lr) * BK +
                                             rdslot(kk * 4 + g)];

    if (t + 2 < nk) {
      int nb = cur + 2;
      if (nb >= 3) nb -= 3;
      stage(nb, (t + 2) * BK);
    }

    __builtin_amdgcn_s_setprio(1);
#pragma unroll
    for (int kk = 0; kk < KK; ++kk)
#pragma unroll
      for (int i = 0; i < MI; ++i)
#pragma unroll
        for (int j = 0; j < NJ; ++j)
          acc[i][j] = MFMA16(afr[i][kk], bfr[j][kk], acc[i][j]);
    __builtin_amdgcn_s_setprio(0);

    ++cur;
    if (cur == 3) cur = 0;
  }

#pragma unroll
  for (int i = 0; i < MI; ++i) {
#pragma unroll
    for (int j = 0; j < NJ; ++j) {
      const int r0 = brow + wr * WM + i * 16 + g * 4;
      const int c = bcol + wc * WN + j * 16 + lr;
      if constexpr (EPI == 1) {
        const float bv = bias0[c];
#pragma unroll
        for (int rr = 0; rr < 4; ++rr)
          out0[(size_t)(r0 + rr) * N + c] =
              (bf16)fmaxf(acc[i][j][rr] + bv, 0.0f);
      } else if constexpr (EPI == 5) {
        const float bv = bias0[c];
#pragma unroll
        for (int rr = 0; rr < 4; ++rr) {
          const size_t idx = (size_t)(r0 + rr) * N + c;
          out0[idx] = (bf16)(acc[i][j][rr] + bv + resid[idx]);
        }
      } else if constexpr (EPI == 6) {
        const float bv = bias0[c];
#pragma unroll
        for (int rr = 0; rr < 4; ++rr) {
          const size_t idx = (size_t)(r0 + rr) * N + c;
          outf[idx] = acc[i][j][rr] + bv + (float)residb[idx];
        }
      } else {  // EPI 4: fused QKV
        const int sub = c >> 10;
        const int c1 = c & 1023;
        if (sub == 0) {  // Q, pre-scaled into log2-softmax units
          const float bv = bias0[c1];
#pragma unroll
          for (int rr = 0; rr < 4; ++rr)
            out0[(size_t)(r0 + rr) * 1024 + c1] =
                (bf16)((acc[i][j][rr] + bv) * QSCL);
        } else if (sub == 1) {
          const float bv = bias1[c1];
#pragma unroll
          for (int rr = 0; rr < 4; ++rr)
            out1[(size_t)(r0 + rr) * 1024 + c1] = (bf16)(acc[i][j][rr] + bv);
        } else {
          const float bv = bias2[c1];
          const int bb = r0 >> 11, t0 = r0 & 2047;
          const int hh = c1 >> 6, dd = c1 & 63;
          bf16x4 pk;
#pragma unroll
          for (int rr = 0; rr < 4; ++rr) pk[rr] = (bf16)(acc[i][j][rr] + bv);
          *(bf16x4*)(out2 + ((size_t)((bb * 16 + hh) * 64 + dd)) * 2048 + t0) = pk;
        }
      }
    }
  }
}

// ---------------------------------------------------------------------------
// Causal flash attention, S^T formulation, exp2-softmax (no max-tracking).
// r14-proven body; Pq stride 72 (exact fit) -> LDS 25.6 KB -> 6 blocks/CU.
// ---------------------------------------------------------------------------
__global__ __launch_bounds__(256) void attn_kernel(
    const bf16* __restrict__ q, const bf16* __restrict__ kmat,
    const bf16* __restrict__ vt, bf16* __restrict__ ctx)
{
  __shared__ bf16 Ks[64 * 64];
  __shared__ bf16 Vs[64 * 64];
  __shared__ bf16 Pq[4][16][72];
  const int bx = blockIdx.x, by = blockIdx.y;
  const int k4 = by >> 3;
  const int qt = (k4 == 0) ? bx
               : (k4 == 1) ? (31 - bx)
               : (k4 == 2) ? (bx ^ 16)
                           : (31 - (bx ^ 16));
  const int b_ = by >> 4, h_ = by & 15;
  const int qb = qt * 64;
  const int tid = threadIdx.x;
  const int lane = tid & 63, w = tid >> 6;
  const int g = lane >> 4, lr = lane & 15;
  const int qrow = qb + w * 16 + lr;

  bf16x8 qf[2];
  {
    const bf16* qp = q + (size_t)(b_ * 2048 + qrow) * 1024 + h_ * 64 + g * 8;
    qf[0] = *(const bf16x8*)qp;
    qf[1] = *(const bf16x8*)(qp + 32);
  }

  f32x4 o[4] = {};
  float l = 0.f;

  const int srow = tid >> 2;
  const int c16 = (tid & 3) * 16;
  const int rb = srow * 128;
  const int sw = (srow & 7) << 4;
  const bf16* kbase = kmat + (size_t)(b_ * 2048) * 1024 + h_ * 64;
  const bf16* vbase = vt + (size_t)(b_ * 16 + h_) * 64 * 2048;
  const bf16* kp0 = kbase + (size_t)srow * 1024 + c16;
  const bf16* vp0 = vbase + (size_t)srow * 2048 + c16;

  bf16x8 k0 = *(const bf16x8*)kp0;
  bf16x8 k1 = *(const bf16x8*)(kp0 + 8);
  bf16x8 v0 = *(const bf16x8*)vp0;
  bf16x8 v1 = *(const bf16x8*)(vp0 + 8);

  for (int s0 = 0; s0 <= qb; s0 += 64) {
    *(bf16x8*)((char*)Ks + ((rb + c16 * 2) ^ sw)) = k0;
    *(bf16x8*)((char*)Ks + ((rb + c16 * 2 + 16) ^ sw)) = k1;
    *(bf16x8*)((char*)Vs + ((rb + c16 * 2) ^ sw)) = v0;
    *(bf16x8*)((char*)Vs + ((rb + c16 * 2 + 16) ^ sw)) = v1;
    __syncthreads();
    if (s0 < qb) {  // reg-prefetch next K/V tile
      const bf16* kp = kp0 + (size_t)(s0 + 64) * 1024;
      k0 = *(const bf16x8*)kp;
      k1 = *(const bf16x8*)(kp + 8);
      const bf16* vp = vp0 + (s0 + 64);
      v0 = *(const bf16x8*)vp;
      v1 = *(const bf16x8*)(vp + 8);
    }

    f32x4 st[4];
    __builtin_amdgcn_s_setprio(1);
#pragma unroll
    for (int n = 0; n < 4; ++n) {
      f32x4 z = {};
#pragma unroll
      for (int kk = 0; kk < 2; ++kk) {
        const int row = n * 16 + lr;
        bf16x8 ak = *(const bf16x8*)((char*)Ks +
            ((row * 128 + kk * 64 + g * 16) ^ ((lr & 7) << 4)));
        z = MFMA16(ak, qf[kk], z);
      }
      st[n] = z;
    }
    __builtin_amdgcn_s_setprio(0);

    if (s0 == qb) {  // causal mask on the diagonal tile
#pragma unroll
      for (int n = 0; n < 4; ++n)
#pragma unroll
        for (int r = 0; r < 4; ++r)
          if (s0 + n * 16 + g * 4 + r > qrow) st[n][r] = -1e30f;
    }

    float rs = 0.f;
#pragma unroll
    for (int n = 0; n < 4; ++n) {
      bf16x4 pk;
#pragma unroll
      for (int r = 0; r < 4; ++r) {
        const float p = fexp2(st[n][r]);
        rs += p;
        pk[r] = (bf16)p;
      }
      *(bf16x4*)&Pq[w][lr][n * 16 + g * 4] = pk;
    }

    bf16x8 pa[2];
#pragma unroll
    for (int kk = 0; kk < 2; ++kk)
      pa[kk] = *(const bf16x8*)&Pq[w][lr][kk * 32 + g * 8];
    __builtin_amdgcn_s_setprio(1);
#pragma unroll
    for (int n = 0; n < 4; ++n) {
      const int row = n * 16 + lr;
#pragma unroll
      for (int kk = 0; kk < 2; ++kk) {
        bf16x8 bv = *(const bf16x8*)((char*)Vs +
            ((row * 128 + kk * 64 + g * 16) ^ ((lr & 7) << 4)));
        o[n] = MFMA16(pa[kk], bv, o[n]);
      }
    }
    __builtin_amdgcn_s_setprio(0);

    rs += __shfl_xor(rs, 16);
    rs += __shfl_xor(rs, 32);
    l += rs;
    __syncthreads();
  }

  float lq[4];
#pragma unroll
  for (int r = 0; r < 4; ++r) lq[r] = __shfl(l, g * 4 + r);
#pragma unroll
  for (int r = 0; r < 4; ++r) {
    const float inv = 1.0f / lq[r];
#pragma unroll
    for (int n = 0; n < 4; ++n)
      ctx[(size_t)(b_ * 2048 + qb + w * 16 + g * 4 + r) * 1024 + h_ * 64 + n * 16 + lr] =
          (bf16)(o[n][r] * inv);
  }
}

// ---------------------------------------------------------------------------
extern "C" void kernel_launch(void* const* d_in, const int* in_sizes, int n_in,
                              void* d_out, int out_size, void* d_ws, size_t ws_size,
                              hipStream_t stream)
{
  (void)in_sizes; (void)n_in; (void)out_size; (void)ws_size;
  const float* x   = (const float*)d_in[0];
  const float* Wq  = (const float*)d_in[1];
  const float* bq  = (const float*)d_in[2];
  const float* Wk  = (const float*)d_in[3];
  const float* bk  = (const float*)d_in[4];
  const float* Wv  = (const float*)d_in[5];
  const float* bv  = (const float*)d_in[6];
  const float* Wo  = (const float*)d_in[7];
  const float* bo  = (const float*)d_in[8];
  const float* W1  = (const float*)d_in[9];
  const float* b1  = (const float*)d_in[10];
  const float* W2  = (const float*)d_in[11];
  const float* b2  = (const float*)d_in[12];
  const float* g1  = (const float*)d_in[13];
  const float* be1 = (const float*)d_in[14];
  const float* g2  = (const float*)d_in[15];
  const float* be2 = (const float*)d_in[16];
  float* out = (float*)d_out;

  char* ws = (char*)d_ws;
  const size_t MB = 1024 * 1024;
  bf16* wqkv_t = (bf16*)(ws + 0 * MB);  // [3072][1024]: wq|wk|wv contiguous
  bf16* wo_t = (bf16*)(ws + 6 * MB);
  bf16* w1_t = (bf16*)(ws + 8 * MB);   // [4096][1024]
  bf16* w2_t = (bf16*)(ws + 16 * MB);  // [1024][4096]
  bf16* h1   = (bf16*)(ws + 24 * MB);  // [4096][1024]
  bf16* qbuf = (bf16*)(ws + 32 * MB);  // [4096][1024]
  bf16* kbuf = (bf16*)(ws + 40 * MB);  // [4096][1024]
  bf16* vtb  = (bf16*)(ws + 48 * MB);  // [2][16][64][2048]
  bf16* ctx  = (bf16*)(ws + 56 * MB);  // [4096][1024]
  bf16* h2   = (bf16*)(ws + 64 * MB);  // [4096][1024]
  bf16* x2b  = (bf16*)(ws + 72 * MB);  // [4096][1024] bf16 x2
  bf16* ff1  = (bf16*)(ws + 24 * MB);  // [4096][4096], overlays h1/q/k/vtb (dead)

  // transposes + LN1 fused in one launch (12288 + 4096 blocks)
  prologue_kernel<<<16384, dim3(32, 8), 0, stream>>>(
      Wq, Wk, Wv, Wo, wqkv_t, W1, w1_t, W2, w2_t, x, g1, be1, h1);

  // fused QKV: -> q(prescaled), k, v(transposed)  [128x128, BK=32, XCD swz]
  gemm_bt<128, 128, 32, 4, 1><<<dim3(24, 32), 256, 0, stream>>>(
      h1, wqkv_t, bq, bk, bv, nullptr, nullptr, qbuf, kbuf, vtb, nullptr,
      4096, 3072, 1024);

  // CU-balanced attention: grid (32,32), 66 s-tiles per CU
  attn_kernel<<<dim3(32, 32), 256, 0, stream>>>(qbuf, kbuf, vtb, ctx);

  // x2 = x + ctx@Wo + bo -> bf16 x2b   [128x64, BK=64, 2/CU, EPI 5]
  gemm_bt<128, 64, 64, 5, 0><<<dim3(16, 32), 256, 0, stream>>>(
      ctx, wo_t, bo, nullptr, nullptr, x, nullptr, x2b, nullptr, nullptr,
      nullptr, 4096, 1024, 1024);

  ln_b_kernel<<<4096, 256, 0, stream>>>(x2b, g2, be2, h2);

  // ff1 = relu(h2 @ W1 + b1)  [256x128, BK=32, 2/CU, XCD swz]
  gemm_bt<256, 128, 32, 1, 1><<<dim3(32, 16), 256, 0, stream>>>(
      h2, w1_t, b1, nullptr, nullptr, nullptr, nullptr, ff1, nullptr, nullptr,
      nullptr, 4096, 4096, 1024);

  // out = x2b + ff1@W2 + b2 -> d_out (f32)  [128x64, BK=64, XCD swz, EPI 6]
  gemm_bt<128, 64, 64, 6, 1><<<dim3(16, 32), 256, 0, stream>>>(
      ff1, w2_t, b2, nullptr, nullptr, nullptr, x2b, nullptr, nullptr, nullptr,
      out, 4096, 1024, 4096);
}

// Round 20
// 188.433 us; speedup vs baseline: 1.4696x; 1.0356x over previous
//
#include <hip/hip_runtime.h>

typedef __bf16 bf16;
typedef __attribute__((ext_vector_type(8))) __bf16 bf16x8;
typedef __attribute__((ext_vector_type(4))) __bf16 bf16x4;
typedef __attribute__((ext_vector_type(4))) float f32x4;

#define MFMA16(A, B, C) __builtin_amdgcn_mfma_f32_16x16x32_bf16(A, B, C, 0, 0, 0)

// async global->LDS, 16B per lane: dest = (wave-uniform base) + lane*16
#define GLOAD16(gp, lp)                                          \
  __builtin_amdgcn_global_load_lds(                              \
      (const __attribute__((address_space(1))) void*)(gp),       \
      (__attribute__((address_space(3))) void*)(lp), 16, 0, 0)

// 2^x (v_exp_f32 computes 2^S0)
__device__ __forceinline__ float fexp2(float x) {
#if __has_builtin(__builtin_amdgcn_exp2f)
  return __builtin_amdgcn_exp2f(x);
#else
  float r;
  asm("v_exp_f32 %0, %1" : "=v"(r) : "v"(x));
  return r;
#endif
}

// Q pre-scale: scores = (q.k)/sqrt(64) in log2 units for exp2-softmax
#define QSCL 0.18033688011112042f  // 0.125 * log2(e)

// ---------------------------------------------------------------------------
// Prologue mega-kernel: all weight transposes (fp32->bf16) + LayerNorm1.
// ---------------------------------------------------------------------------
__global__ __launch_bounds__(256) void prologue_kernel(
    const float* __restrict__ w0, const float* __restrict__ w1,
    const float* __restrict__ w2, const float* __restrict__ w3,
    bf16* __restrict__ out4,
    const float* __restrict__ W1, bf16* __restrict__ w1t,
    const float* __restrict__ W2, bf16* __restrict__ w2t,
    const float* __restrict__ x, const float* __restrict__ gamma,
    const float* __restrict__ beta, bf16* __restrict__ h1)
{
  __shared__ float tile[32][33];
  __shared__ float ssum[4], ssq[4];
  const int bid = blockIdx.x;

  if (bid >= 12288) {  // -------- LayerNorm1 row
    const int row = bid - 12288;
    const int t = threadIdx.y * 32 + threadIdx.x;
    const float4 v = ((const float4*)(x + (size_t)row * 1024))[t];
    float s = v.x + v.y + v.z + v.w;
    float sq = v.x * v.x + v.y * v.y + v.z * v.z + v.w * v.w;
#pragma unroll
    for (int m = 1; m < 64; m <<= 1) {
      s += __shfl_xor(s, m);
      sq += __shfl_xor(sq, m);
    }
    const int wv = t >> 6;
    if ((t & 63) == 0) { ssum[wv] = s; ssq[wv] = sq; }
    __syncthreads();
    s = ssum[0] + ssum[1] + ssum[2] + ssum[3];
    sq = ssq[0] + ssq[1] + ssq[2] + ssq[3];
    const float mu = s * (1.0f / 1024.0f);
    const float var = sq * (1.0f / 1024.0f) - mu * mu;
    const float rs = rsqrtf(var + 1e-3f);
    const float4 g = ((const float4*)gamma)[t];
    const float4 b = ((const float4*)beta)[t];
    bf16x4 o;
    o[0] = (bf16)((v.x - mu) * rs * g.x + b.x);
    o[1] = (bf16)((v.y - mu) * rs * g.y + b.y);
    o[2] = (bf16)((v.z - mu) * rs * g.z + b.z);
    o[3] = (bf16)((v.w - mu) * rs * g.w + b.w);
    *(bf16x4*)(h1 + (size_t)row * 1024 + t * 4) = o;
    return;
  }

  // -------- weight transpose tile
  const float* in;
  bf16* out;
  int K, N, kt, nt;
  if (bid < 4096) {
    const float* srcs[4] = {w0, w1, w2, w3};
    in = srcs[bid >> 10];
    out = out4 + (size_t)(bid >> 10) * 1024 * 1024;
    K = 1024; N = 1024;
    const int t = bid & 1023;
    nt = (t & 31) * 32; kt = (t >> 5) * 32;
  } else if (bid < 8192) {
    in = W1; out = w1t; K = 1024; N = 4096;
    const int t = bid - 4096;
    nt = (t & 127) * 32; kt = (t >> 7) * 32;
  } else {
    in = W2; out = w2t; K = 4096; N = 1024;
    const int t = bid - 8192;
    nt = (t & 31) * 32; kt = (t >> 5) * 32;
  }
  const int tx = threadIdx.x, ty = threadIdx.y;
#pragma unroll
  for (int j = 0; j < 4; ++j)
    tile[ty + j * 8][tx] = in[(size_t)(kt + ty + j * 8) * N + nt + tx];
  __syncthreads();
#pragma unroll
  for (int j = 0; j < 4; ++j)
    out[(size_t)(nt + ty + j * 8) * K + kt + tx] = (bf16)tile[tx][ty + j * 8];
}

// LayerNorm, bf16 in -> bf16 out (for the bf16 x2 chain)
__global__ __launch_bounds__(256) void ln_b_kernel(
    const bf16* __restrict__ in, const float* __restrict__ gamma,
    const float* __restrict__ beta, bf16* __restrict__ out)
{
  const int row = blockIdx.x;
  const int t = threadIdx.x;
  const bf16x4 vb = *(const bf16x4*)(in + (size_t)row * 1024 + t * 4);
  float v0 = (float)vb[0], v1 = (float)vb[1], v2 = (float)vb[2], v3 = (float)vb[3];
  float s = v0 + v1 + v2 + v3;
  float sq = v0 * v0 + v1 * v1 + v2 * v2 + v3 * v3;
#pragma unroll
  for (int m = 1; m < 64; m <<= 1) {
    s += __shfl_xor(s, m);
    sq += __shfl_xor(sq, m);
  }
  __shared__ float ssum[4], ssq[4];
  const int w = t >> 6;
  if ((t & 63) == 0) { ssum[w] = s; ssq[w] = sq; }
  __syncthreads();
  s = ssum[0] + ssum[1] + ssum[2] + ssum[3];
  sq = ssq[0] + ssq[1] + ssq[2] + ssq[3];
  const float mu = s * (1.0f / 1024.0f);
  const float var = sq * (1.0f / 1024.0f) - mu * mu;
  const float rs = rsqrtf(var + 1e-3f);
  const float4 g = ((const float4*)gamma)[t];
  const float4 b = ((const float4*)beta)[t];
  bf16x4 o;
  o[0] = (bf16)((v0 - mu) * rs * g.x + b.x);
  o[1] = (bf16)((v1 - mu) * rs * g.y + b.y);
  o[2] = (bf16)((v2 - mu) * rs * g.z + b.z);
  o[3] = (bf16)((v3 - mu) * rs * g.w + b.w);
  *(bf16x4*)(out + (size_t)row * 1024 + t * 4) = o;
}

// ---------------------------------------------------------------------------
// GEMM: C[M,N] = epilogue(A[M,K] @ Bt[N,K]^T + bias)   (r16-proven)
// ---------------------------------------------------------------------------
template <int BM, int BN, int BK, int EPI, int SWZ>
__global__ __launch_bounds__(256, 2) void gemm_bt(
    const bf16* __restrict__ A, const bf16* __restrict__ Bt,
    const float* __restrict__ bias0, const float* __restrict__ bias1,
    const float* __restrict__ bias2, const float* __restrict__ resid,
    const bf16* __restrict__ residb,
    bf16* __restrict__ out0, bf16* __restrict__ out1, bf16* __restrict__ out2,
    float* __restrict__ outf, int M, int N, int K)
{
  constexpr int WM = BM / 2, WN = BN / 2;
  constexpr int MI = WM / 16, NJ = WN / 16;
  constexpr int KK = BK / 32;
  constexpr int NSLOT = BK / 8;
  constexpr int SMASK = NSLOT - 1;
  constexpr int RPL = 512 / BK;             // rows per gload16
  constexpr int ALOADS = BM / (4 * RPL);
  constexpr int BLOADS = BN / (4 * RPL);
  constexpr int S = ALOADS + BLOADS;

  __shared__ bf16 As[3][BM * BK];
  __shared__ bf16 Bs[3][BN * BK];
  const int tid = threadIdx.x;
  const int lane = tid & 63, w = tid >> 6;
  const int wr = w >> 1, wc = w & 1;
  const int g = lane >> 4, lr = lane & 15;

  int bx = blockIdx.x, by = blockIdx.y;
  if constexpr (SWZ) {  // XCD by-chunking
    const int bid = bx + gridDim.x * by;
    const int xcd = bid & 7, idx = bid >> 3;
    const int chunk = gridDim.y >> 3;
    by = xcd * chunk + (idx % chunk);
    bx = idx / chunk;
  }
  const int brow = by * BM, bcol = bx * BN;

  f32x4 acc[MI][NJ] = {};

  const int lrow = lane / NSLOT;
  const int slot = lane & SMASK;
  int lcol;
  if constexpr (BK == 32)
    lcol = ((slot - (lrow >> 1)) & 3) * 8;  // rotation involution
  else
    lcol = (slot ^ (lrow & 7)) * 8;         // XOR

  auto stage = [&](int buf, int k0) {
#pragma unroll
    for (int j = 0; j < ALOADS; ++j) {
      const int row0 = w * (BM / 4) + j * RPL;
      GLOAD16(A + (size_t)(brow + row0 + lrow) * K + k0 + lcol,
              &As[buf][row0 * BK]);
    }
#pragma unroll
    for (int j = 0; j < BLOADS; ++j) {
      const int row0 = w * (BN / 4) + j * RPL;
      GLOAD16(Bt + (size_t)(bcol + row0 + lrow) * K + k0 + lcol,
              &Bs[buf][row0 * BK]);
    }
  };

  auto rdslot = [&](int kg) {
    if constexpr (BK == 32) return ((kg + (lr >> 1)) & 3) * 8;
    else return (kg ^ (lr & 7)) * 8;
  };

  const int nk = K / BK;
  stage(0, 0);
  stage(1, BK);
  int cur = 0;
  for (int t = 0; t < nk; ++t) {
    if (t + 1 < nk) {
      if constexpr (S == 3)
        asm volatile("s_waitcnt vmcnt(3)" ::: "memory");
      else if constexpr (S == 4)
        asm volatile("s_waitcnt vmcnt(4)" ::: "memory");
      else
        asm volatile("s_waitcnt vmcnt(6)" ::: "memory");
    } else {
      asm volatile("s_waitcnt vmcnt(0)" ::: "memory");
    }
    __builtin_amdgcn_s_barrier();
    __builtin_amdgcn_sched_barrier(0);

    bf16x8 afr[MI][KK], bfr[NJ][KK];
#pragma unroll
    for (int i = 0; i < MI; ++i)
#pragma unroll
      for (int kk = 0; kk < KK; ++kk)
        afr[i][kk] = *(const bf16x8*)&As[cur][(wr * WM + i * 16 + lr) * BK +
                                             rdslot(kk * 4 + g)];
#pragma unroll
    for (int j = 0; j < NJ; ++j)
#pragma unroll
      for (int kk = 0; kk < KK; ++kk)
        bfr[j][kk] = *(const bf16x8*)&Bs[cur][(wc * WN + j * 16 + lr) * BK +
                                             rdslot(kk * 4 + g)];

    if (t + 2 < nk) {
      int nb = cur + 2;
      if (nb >= 3) nb -= 3;
      stage(nb, (t + 2) * BK);
    }

    __builtin_amdgcn_s_setprio(1);
#pragma unroll
    for (int kk = 0; kk < KK; ++kk)
#pragma unroll
      for (int i = 0; i < MI; ++i)
#pragma unroll
        for (int j = 0; j < NJ; ++j)
          acc[i][j] = MFMA16(afr[i][kk], bfr[j][kk], acc[i][j]);
    __builtin_amdgcn_s_setprio(0);

    ++cur;
    if (cur == 3) cur = 0;
  }

#pragma unroll
  for (int i = 0; i < MI; ++i) {
#pragma unroll
    for (int j = 0; j < NJ; ++j) {
      const int r0 = brow + wr * WM + i * 16 + g * 4;
      const int c = bcol + wc * WN + j * 16 + lr;
      if constexpr (EPI == 1) {
        const float bv = bias0[c];
#pragma unroll
        for (int rr = 0; rr < 4; ++rr)
          out0[(size_t)(r0 + rr) * N + c] =
              (bf16)fmaxf(acc[i][j][rr] + bv, 0.0f);
      } else if constexpr (EPI == 5) {
        const float bv = bias0[c];
#pragma unroll
        for (int rr = 0; rr < 4; ++rr) {
          const size_t idx = (size_t)(r0 + rr) * N + c;
          out0[idx] = (bf16)(acc[i][j][rr] + bv + resid[idx]);
        }
      } else if constexpr (EPI == 6) {
        const float bv = bias0[c];
#pragma unroll
        for (int rr = 0; rr < 4; ++rr) {
          const size_t idx = (size_t)(r0 + rr) * N + c;
          outf[idx] = acc[i][j][rr] + bv + (float)residb[idx];
        }
      } else {  // EPI 4: fused QKV
        const int sub = c >> 10;
        const int c1 = c & 1023;
        if (sub == 0) {
          const float bv = bias0[c1];
#pragma unroll
          for (int rr = 0; rr < 4; ++rr)
            out0[(size_t)(r0 + rr) * 1024 + c1] =
                (bf16)((acc[i][j][rr] + bv) * QSCL);
        } else if (sub == 1) {
          const float bv = bias1[c1];
#pragma unroll
          for (int rr = 0; rr < 4; ++rr)
            out1[(size_t)(r0 + rr) * 1024 + c1] = (bf16)(acc[i][j][rr] + bv);
        } else {
          const float bv = bias2[c1];
          const int bb = r0 >> 11, t0 = r0 & 2047;
          const int hh = c1 >> 6, dd = c1 & 63;
          bf16x4 pk;
#pragma unroll
          for (int rr = 0; rr < 4; ++rr) pk[rr] = (bf16)(acc[i][j][rr] + bv);
          *(bf16x4*)(out2 + ((size_t)((bb * 16 + hh) * 64 + dd)) * 2048 + t0) = pk;
        }
      }
    }
  }
}

// ---------------------------------------------------------------------------
// Causal flash attention v9: QBLK=128 via 8 waves/block (512 thr).
// Per-wave code identical to the r14-proven body (VGPR unchanged); 128 q-rows
// share ONE K/V stage -> per-CU serial iteration count halves (34 vs 66),
// staging bytes/thread halve, K/V HBM fetch ~halves.
// Wave group wg=w>>2 handles qt = 2a+wg (ww=w&3 indexes 16-row slices).
// Paired map a = (by>>4)?(15-bx):bx -> per-CU iters = (2bx+2)+(2(15-bx)+2)=34.
// Group-0 waves skip the final (fully-masked) tile via wave-uniform guard.
// ---------------------------------------------------------------------------
__global__ __launch_bounds__(512) void attn_kernel(
    const bf16* __restrict__ q, const bf16* __restrict__ kmat,
    const bf16* __restrict__ vt, bf16* __restrict__ ctx)
{
  __shared__ bf16 Ks[64 * 64];
  __shared__ bf16 Vs[64 * 64];
  __shared__ bf16 Pq[8][16][72];
  const int bx = blockIdx.x, by = blockIdx.y;
  const int k2 = by >> 4;
  const int a = k2 ? (15 - bx) : bx;       // qt pair index 0..15
  const int b_ = by >> 4, h_ = by & 15;
  const int tid = threadIdx.x;
  const int lane = tid & 63, w = tid >> 6;  // 8 waves
  const int wg = w >> 2, ww = w & 3;        // group (qt), slice within group
  const int g = lane >> 4, lr = lane & 15;
  const int qt = 2 * a + wg;
  const int qb = qt * 64;
  const int qrow = qb + ww * 16 + lr;       // this lane's q row

  bf16x8 qf[2];
  {
    const bf16* qp = q + (size_t)(b_ * 2048 + qrow) * 1024 + h_ * 64 + g * 8;
    qf[0] = *(const bf16x8*)qp;
    qf[1] = *(const bf16x8*)(qp + 32);
  }

  f32x4 o[4] = {};
  float l = 0.f;

  // staging: 512 threads, one bf16x8 (16B) each for K and V
  const int srow = tid >> 3;            // 0..63
  const int c8 = (tid & 7) * 8;         // element offset 0..56
  const int rb = srow * 128;
  const int sw = (srow & 7) << 4;
  const bf16* kbase = kmat + (size_t)(b_ * 2048) * 1024 + h_ * 64;
  const bf16* vbase = vt + (size_t)(b_ * 16 + h_) * 64 * 2048;
  const bf16* kp0 = kbase + (size_t)srow * 1024 + c8;
  const bf16* vp0 = vbase + (size_t)srow * 2048 + c8;

  bf16x8 k0 = *(const bf16x8*)kp0;
  bf16x8 v0 = *(const bf16x8*)vp0;

  const int ns = 2 * a + 2;  // s-tiles processed by this block
  for (int t = 0; t < ns; ++t) {
    const int s0 = t << 6;
    *(bf16x8*)((char*)Ks + ((rb + c8 * 2) ^ sw)) = k0;
    *(bf16x8*)((char*)Vs + ((rb + c8 * 2) ^ sw)) = v0;
    __syncthreads();
    if (t + 1 < ns) {  // reg-prefetch next K/V tile
      k0 = *(const bf16x8*)(kp0 + (size_t)(s0 + 64) * 1024);
      v0 = *(const bf16x8*)(vp0 + (s0 + 64));
    }

    if (s0 <= qb) {  // wave-uniform: group 0 skips the final masked tile
      f32x4 st[4];
      __builtin_amdgcn_s_setprio(1);
#pragma unroll
      for (int n = 0; n < 4; ++n) {
        f32x4 z = {};
#pragma unroll
        for (int kk = 0; kk < 2; ++kk) {
          const int row = n * 16 + lr;
          bf16x8 ak = *(const bf16x8*)((char*)Ks +
              ((row * 128 + kk * 64 + g * 16) ^ ((lr & 7) << 4)));
          z = MFMA16(ak, qf[kk], z);
        }
        st[n] = z;
      }
      __builtin_amdgcn_s_setprio(0);

      if (s0 == qb) {  // causal mask on the diagonal tile
#pragma unroll
        for (int n = 0; n < 4; ++n)
#pragma unroll
          for (int r = 0; r < 4; ++r)
            if (s0 + n * 16 + g * 4 + r > qrow) st[n][r] = -1e30f;
      }

      float rs = 0.f;
#pragma unroll
      for (int n = 0; n < 4; ++n) {
        bf16x4 pk;
#pragma unroll
        for (int r = 0; r < 4; ++r) {
          const float p = fexp2(st[n][r]);
          rs += p;
          pk[r] = (bf16)p;
        }
        *(bf16x4*)&Pq[w][lr][n * 16 + g * 4] = pk;
      }

      bf16x8 pa[2];
#pragma unroll
      for (int kk = 0; kk < 2; ++kk)
        pa[kk] = *(const bf16x8*)&Pq[w][lr][kk * 32 + g * 8];
      __builtin_amdgcn_s_setprio(1);
#pragma unroll
      for (int n = 0; n < 4; ++n) {
        const int row = n * 16 + lr;
#pragma unroll
        for (int kk = 0; kk < 2; ++kk) {
          bf16x8 bv = *(const bf16x8*)((char*)Vs +
              ((row * 128 + kk * 64 + g * 16) ^ ((lr & 7) << 4)));
          o[n] = MFMA16(pa[kk], bv, o[n]);
        }
      }
      __builtin_amdgcn_s_setprio(0);

      rs += __shfl_xor(rs, 16);
      rs += __shfl_xor(rs, 32);
      l += rs;
    }
    __syncthreads();
  }

  float lq[4];
#pragma unroll
  for (int r = 0; r < 4; ++r) lq[r] = __shfl(l, g * 4 + r);
#pragma unroll
  for (int r = 0; r < 4; ++r) {
    const float inv = 1.0f / lq[r];
#pragma unroll
    for (int n = 0; n < 4; ++n)
      ctx[(size_t)(b_ * 2048 + qb + ww * 16 + g * 4 + r) * 1024 + h_ * 64 +
          n * 16 + lr] = (bf16)(o[n][r] * inv);
  }
}

// ---------------------------------------------------------------------------
extern "C" void kernel_launch(void* const* d_in, const int* in_sizes, int n_in,
                              void* d_out, int out_size, void* d_ws, size_t ws_size,
                              hipStream_t stream)
{
  (void)in_sizes; (void)n_in; (void)out_size; (void)ws_size;
  const float* x   = (const float*)d_in[0];
  const float* Wq  = (const float*)d_in[1];
  const float* bq  = (const float*)d_in[2];
  const float* Wk  = (const float*)d_in[3];
  const float* bk  = (const float*)d_in[4];
  const float* Wv  = (const float*)d_in[5];
  const float* bv  = (const float*)d_in[6];
  const float* Wo  = (const float*)d_in[7];
  const float* bo  = (const float*)d_in[8];
  const float* W1  = (const float*)d_in[9];
  const float* b1  = (const float*)d_in[10];
  const float* W2  = (const float*)d_in[11];
  const float* b2  = (const float*)d_in[12];
  const float* g1  = (const float*)d_in[13];
  const float* be1 = (const float*)d_in[14];
  const float* g2  = (const float*)d_in[15];
  const float* be2 = (const float*)d_in[16];
  float* out = (float*)d_out;

  char* ws = (char*)d_ws;
  const size_t MB = 1024 * 1024;
  bf16* wqkv_t = (bf16*)(ws + 0 * MB);  // [3072][1024]: wq|wk|wv contiguous
  bf16* wo_t = (bf16*)(ws + 6 * MB);
  bf16* w1_t = (bf16*)(ws + 8 * MB);   // [4096][1024]
  bf16* w2_t = (bf16*)(ws + 16 * MB);  // [1024][4096]
  bf16* h1   = (bf16*)(ws + 24 * MB);  // [4096][1024]
  bf16* qbuf = (bf16*)(ws + 32 * MB);  // [4096][1024]
  bf16* kbuf = (bf16*)(ws + 40 * MB);  // [4096][1024]
  bf16* vtb  = (bf16*)(ws + 48 * MB);  // [2][16][64][2048]
  bf16* ctx  = (bf16*)(ws + 56 * MB);  // [4096][1024]
  bf16* h2   = (bf16*)(ws + 64 * MB);  // [4096][1024]
  bf16* x2b  = (bf16*)(ws + 72 * MB);  // [4096][1024] bf16 x2
  bf16* ff1  = (bf16*)(ws + 24 * MB);  // [4096][4096], overlays h1/q/k/vtb (dead)

  // transposes + LN1 fused in one launch (12288 + 4096 blocks)
  prologue_kernel<<<16384, dim3(32, 8), 0, stream>>>(
      Wq, Wk, Wv, Wo, wqkv_t, W1, w1_t, W2, w2_t, x, g1, be1, h1);

  // fused QKV: -> q(prescaled), k, v(transposed)  [128x128, BK=32, XCD swz]
  gemm_bt<128, 128, 32, 4, 1><<<dim3(24, 32), 256, 0, stream>>>(
      h1, wqkv_t, bq, bk, bv, nullptr, nullptr, qbuf, kbuf, vtb, nullptr,
      4096, 3072, 1024);

  // QBLK=128 8-wave attention: grid (16,32), 34 s-tile iters per CU
  attn_kernel<<<dim3(16, 32), 512, 0, stream>>>(qbuf, kbuf, vtb, ctx);

  // x2 = x + ctx@Wo + bo -> bf16 x2b   [128x64, BK=64, 2/CU, EPI 5]
  gemm_bt<128, 64, 64, 5, 0><<<dim3(16, 32), 256, 0, stream>>>(
      ctx, wo_t, bo, nullptr, nullptr, x, nullptr, x2b, nullptr, nullptr,
      nullptr, 4096, 1024, 1024);

  ln_b_kernel<<<4096, 256, 0, stream>>>(x2b, g2, be2, h2);

  // ff1 = relu(h2 @ W1 + b1)  [256x128, BK=32, 2/CU, XCD swz]
  gemm_bt<256, 128, 32, 1, 1><<<dim3(32, 16), 256, 0, stream>>>(
      h2, w1_t, b1, nullptr, nullptr, nullptr, nullptr, ff1, nullptr, nullptr,
      nullptr, 4096, 4096, 1024);

  // out = x2b + ff1@W2 + b2 -> d_out (f32)  [128x64, BK=64, XCD swz, EPI 6]
  gemm_bt<128, 64, 64, 6, 1><<<dim3(16, 32), 256, 0, stream>>>(
      ff1, w2_t, b2, nullptr, nullptr, nullptr, x2b, nullptr, nullptr, nullptr,
      out, 4096, 1024, 4096);
}